// Round 7
// baseline (239.094 us; speedup 1.0000x reference)
//
#include <hip/hip_runtime.h>
#include <math.h>

#define EPS 1e-7f

constexpr int B = 16, L = 1024, D = 256, P = 20;
constexpr int LD = L * D;     // 262144
constexpr int DD = D * D;     // 65536

typedef __attribute__((ext_vector_type(8))) short bf16x8;
typedef __attribute__((ext_vector_type(4))) float f32x4;

// ---------------------------------------------------------------------------
// ws layout (float slots):
//   n1    @0         16384     fp32 [B*L]
//   invn2 @16384     16384     fp32 [B*L]
//   t     @32768     4096      fp32 [B*D]   (memset 0, atomic from split2)
//   invU  @36864     16384     fp32 [B*L]
//   rnv1  @53248     327680    fp32 [B*L][P]
//   s1h   @380928    2097152   bf16 [B*L][D]
//   s1l   @2478080   2097152   bf16 [B*L][D]
//   ChT   @4575232   2097152   bf16 [B][D][L]  (s2*sqrt(invn2), transposed, hi)
//   ClT   @6672384   2097152   bf16 [B][D][L]  (lo)
//   Gh    @8769536   524288    bf16 [B][D][D]
//   Gl    @9293824   524288    bf16 [B][D][D]
//   Gp    @9818112   8388608   fp32 [8][B][D][D]  gram K-split partials
//   mav   @18206720  4194304   fp32 [B*L][D]
// total 22401024 floats = 89.6 MB
// ---------------------------------------------------------------------------

__device__ inline void bf16split(float x, unsigned short &h, unsigned short &l) {
    union { float f; unsigned u; } a; a.f = x;
    unsigned hu = (a.u + 0x7FFFu + ((a.u >> 16) & 1u)) & 0xFFFF0000u;
    union { unsigned u; float f; } hb; hb.u = hu;
    h = (unsigned short)(hu >> 16);
    float r = x - hb.f;
    union { float f; unsigned u; } c; c.f = r;
    l = (unsigned short)((c.u + 0x7FFFu + ((c.u >> 16) & 1u)) >> 16);
}

// K1: per-row L2 norms; also emits bf16 hi/lo split of s1.
__global__ __launch_bounds__(256) void k_norms(const float* __restrict__ s1,
                                               const float* __restrict__ s2,
                                               float* __restrict__ n1,
                                               float* __restrict__ invn2,
                                               unsigned short* __restrict__ s1h,
                                               unsigned short* __restrict__ s1l) {
    int tid  = threadIdx.x;
    int lane = tid & 63, w = tid >> 6;
    int row  = blockIdx.x * 4 + w;            // 0..32767
    int r    = (row < B * L) ? row : row - B * L;
    const float* src = (row < B * L) ? s1 : s2;
    float4 v = *(const float4*)(src + (size_t)r * D + lane * 4);
    float s = v.x * v.x + v.y * v.y + v.z * v.z + v.w * v.w;
#pragma unroll
    for (int o = 32; o; o >>= 1) s += __shfl_down(s, o);
    if (row < B * L) {
        ushort4 h4, l4;
        bf16split(v.x, h4.x, l4.x);
        bf16split(v.y, h4.y, l4.y);
        bf16split(v.z, h4.z, l4.z);
        bf16split(v.w, h4.w, l4.w);
        *(ushort4*)(s1h + (size_t)r * D + lane * 4) = h4;
        *(ushort4*)(s1l + (size_t)r * D + lane * 4) = l4;
    }
    if (lane == 0) {
        float n = sqrtf(fmaxf(s, EPS));
        if (row < B * L) n1[r] = n;
        else             invn2[r] = 1.0f / n;
    }
}

// K2: transpose+split C = s2*sqrt(invn2) -> ChT/ClT [B][D][L] bf16; ALSO
// accumulates t[b,d] += sum_m s2[b,m,d]*invn2[b,m] (fused, atomic).
__global__ __launch_bounds__(256) void k_split2(const float* __restrict__ s2,
                                                const float* __restrict__ invn2,
                                                unsigned short* __restrict__ ChT,
                                                unsigned short* __restrict__ ClT,
                                                float* __restrict__ t) {
    __shared__ float tile[64][65];
    __shared__ float wsh[64];    // sqrt(invn2)
    __shared__ float wsh2[64];   // invn2
    int tid = threadIdx.x;
    int b   = blockIdx.x >> 6;
    int rem = blockIdx.x & 63;
    int mt  = rem >> 2, dt = rem & 3;
    int m0  = mt * 64, d0 = dt * 64;
    {
        int r = tid >> 2, cs = (tid & 3) * 16;
        const float* gp = s2 + (size_t)b * LD + (size_t)(m0 + r) * D + d0 + cs;
        float4 v0 = ((const float4*)gp)[0];
        float4 v1 = ((const float4*)gp)[1];
        float4 v2 = ((const float4*)gp)[2];
        float4 v3 = ((const float4*)gp)[3];
        *(float4*)&tile[r][cs]      = v0;
        *(float4*)&tile[r][cs + 4]  = v1;
        *(float4*)&tile[r][cs + 8]  = v2;
        *(float4*)&tile[r][cs + 12] = v3;
        if (tid < 64) {
            float iv = invn2[b * L + m0 + tid];
            wsh2[tid] = iv;
            wsh[tid]  = sqrtf(iv);
        }
    }
    __syncthreads();
    int dc = tid >> 2, ms = (tid & 3) * 16;
    union { unsigned short us[16]; uint4 q[2]; } pCh, pCl;
    float tpart = 0.f;
#pragma unroll
    for (int k = 0; k < 16; ++k) {
        int m = ms + k;
        float v = tile[m][dc];
        tpart += v * wsh2[m];
        float wv = v * wsh[m];
        bf16split(wv, pCh.us[k], pCl.us[k]);
    }
    size_t o = (size_t)b * LD + (size_t)(d0 + dc) * L + m0 + ms;
    *(uint4*)(ChT + o) = pCh.q[0]; *(uint4*)(ChT + o + 8) = pCh.q[1];
    *(uint4*)(ClT + o) = pCl.q[0]; *(uint4*)(ClT + o + 8) = pCl.q[1];
    atomicAdd(&t[b * D + d0 + dc], tpart);
}

// K3: invU[row] = 1/(s1.t + eps*n1), rnv1[row][p] = rsqrt(max(s1^2.k2p, eps)).
__global__ __launch_bounds__(256) void k_u(const float* __restrict__ s1,
                                           const float* __restrict__ t,
                                           const float* __restrict__ n1,
                                           const float* __restrict__ kern,
                                           float* __restrict__ invU,
                                           float* __restrict__ rnv1) {
    __shared__ float k2s[P * D];   // 20 KB
    int tid = threadIdx.x;
#pragma unroll
    for (int p = 0; p < P; ++p) {
        float v = kern[p * D + tid];
        k2s[p * D + tid] = v * v;
    }
    __syncthreads();

    int w = tid >> 6, lane = tid & 63;
    int row = blockIdx.x * 4 + w;             // 0..16383
    int b   = row >> 10;
    int dg = lane & 15, ps = lane >> 4;

    float4 sv[4], ss[4];
    float up = 0.f;
#pragma unroll
    for (int j = 0; j < 4; ++j) {
        sv[j] = *(const float4*)(s1 + (size_t)row * D + dg * 4 + j * 64);
        float4 tv = *(const float4*)(t + b * D + dg * 4 + j * 64);
        up += sv[j].x * tv.x + sv[j].y * tv.y + sv[j].z * tv.z + sv[j].w * tv.w;
        ss[j].x = sv[j].x * sv[j].x; ss[j].y = sv[j].y * sv[j].y;
        ss[j].z = sv[j].z * sv[j].z; ss[j].w = sv[j].w * sv[j].w;
    }
#pragma unroll
    for (int o = 8; o; o >>= 1) up += __shfl_down(up, o, 16);
    if (dg == 0 && ps == 0) invU[row] = 1.0f / (up + EPS * n1[row]);
#pragma unroll
    for (int tI = 0; tI < 5; ++tI) {
        int p = ps + tI * 4;
        float nb = 0.f;
#pragma unroll
        for (int j = 0; j < 4; ++j) {
            float4 kv = *(const float4*)&k2s[p * D + j * 64 + dg * 4];
            nb += ss[j].x * kv.x + ss[j].y * kv.y + ss[j].z * kv.z + ss[j].w * kv.w;
        }
#pragma unroll
        for (int o = 8; o; o >>= 1) nb += __shfl_down(nb, o, 16);
        if (dg == 0) rnv1[(size_t)row * P + p] = rsqrtf(fmaxf(nb, EPS));
    }
}

// K4: Gram via MFMA, NO LDS — fragments loaded directly from L2.
// Wave = 64x64 out tile (4x4 MFMA 16x16x32), block = 4 waves (128x128),
// K-split x8 (128 m per kc).  Grid: 16 b x (2 ti x 2 tj) x 8 kc = 512.
__global__ __launch_bounds__(256) void k_gram_mfma(const unsigned short* __restrict__ ChT,
                                                   const unsigned short* __restrict__ ClT,
                                                   float* __restrict__ Gp) {
    int tid  = threadIdx.x;
    int b    = blockIdx.x >> 5;
    int rem  = blockIdx.x & 31;
    int kc   = rem & 7;
    int ti   = (rem >> 4) & 1, tj = (rem >> 3) & 1;
    int wave = tid >> 6, lane = tid & 63;
    int wr   = (wave >> 1) * 64, wcc = (wave & 1) * 64;
    int lr   = lane & 15, lq = lane >> 4;
    int r0   = ti * 128 + wr;
    int c0   = tj * 128 + wcc;
    size_t bo = (size_t)b * LD;

    f32x4 acc[4][4];
#pragma unroll
    for (int i = 0; i < 4; ++i)
#pragma unroll
        for (int j = 0; j < 4; ++j) acc[i][j] = (f32x4){0.f, 0.f, 0.f, 0.f};

#pragma unroll 1
    for (int tau = 0; tau < 3; ++tau) {
        const unsigned short* Ap = (tau < 2) ? ChT : ClT;
        const unsigned short* Bp = (tau == 1) ? ClT : ChT;
        const unsigned short* arow = Ap + bo + (size_t)(r0 + lr) * L + lq * 8 + kc * 128;
        const unsigned short* brow = Bp + bo + (size_t)(c0 + lr) * L + lq * 8 + kc * 128;
#pragma unroll
        for (int kk = 0; kk < 128; kk += 32) {
            bf16x8 af[4], bfr[4];
#pragma unroll
            for (int i = 0; i < 4; ++i)
                af[i] = *(const bf16x8*)(arow + (size_t)i * 16 * L + kk);
#pragma unroll
            for (int j = 0; j < 4; ++j)
                bfr[j] = *(const bf16x8*)(brow + (size_t)j * 16 * L + kk);
#pragma unroll
            for (int i = 0; i < 4; ++i)
#pragma unroll
                for (int j = 0; j < 4; ++j)
                    acc[i][j] = __builtin_amdgcn_mfma_f32_16x16x32_bf16(af[i], bfr[j], acc[i][j], 0, 0, 0);
        }
    }
    float* gout = Gp + ((size_t)(kc * B + b)) * DD;
#pragma unroll
    for (int i = 0; i < 4; ++i)
#pragma unroll
        for (int r = 0; r < 4; ++r) {
            int row = r0 + i * 16 + lq * 4 + r;
#pragma unroll
            for (int j = 0; j < 4; ++j)
                gout[(size_t)row * D + c0 + j * 16 + lr] = acc[i][j][r];
        }
}

// K5: reduce 8 gram partials; emit bf16 hi/lo split of G.
__global__ __launch_bounds__(256) void k_reduceG(const float* __restrict__ Gp,
                                                 unsigned short* __restrict__ Gh,
                                                 unsigned short* __restrict__ Gl) {
    size_t i = ((size_t)blockIdx.x * 256 + threadIdx.x) * 4;
    float4 s = *(const float4*)(Gp + i);
#pragma unroll
    for (int kc = 1; kc < 8; ++kc) {
        float4 a = *(const float4*)(Gp + (size_t)kc * B * DD + i);
        s.x += a.x; s.y += a.y; s.z += a.z; s.w += a.w;
    }
    ushort4 h4, l4;
    bf16split(s.x, h4.x, l4.x);
    bf16split(s.y, h4.y, l4.y);
    bf16split(s.z, h4.z, l4.z);
    bf16split(s.w, h4.w, l4.w);
    *(ushort4*)(Gh + i) = h4;
    *(ushort4*)(Gl + i) = l4;
}

// K6: mav = (s1 @ G) * invU via MFMA, NO LDS.  Wave = 64l x 32n (4x2 MFMA),
// block = 4 waves (128l x 64n).  Grid: 16 b x 8 lt x 4 nt = 512.
__global__ __launch_bounds__(256) void k_mav_mfma(const unsigned short* __restrict__ s1h,
                                                  const unsigned short* __restrict__ s1l,
                                                  const unsigned short* __restrict__ Gh,
                                                  const unsigned short* __restrict__ Gl,
                                                  const float* __restrict__ invU,
                                                  float* __restrict__ mav) {
    int tid  = threadIdx.x;
    int b    = blockIdx.x >> 5;
    int rem  = blockIdx.x & 31;
    int lt   = rem >> 2, nt = rem & 3;
    int wave = tid >> 6, lane = tid & 63;
    int wl   = (wave >> 1) * 64, wn = (wave & 1) * 32;
    int lr   = lane & 15, lq = lane >> 4;
    int l0   = lt * 128 + wl;          // row base in [0,1024)
    int n0   = nt * 64 + wn;           // col base in [0,256)

    f32x4 acc[4][2];
#pragma unroll
    for (int i = 0; i < 4; ++i)
#pragma unroll
        for (int j = 0; j < 2; ++j) acc[i][j] = (f32x4){0.f, 0.f, 0.f, 0.f};

#pragma unroll 1
    for (int tau = 0; tau < 3; ++tau) {
        const unsigned short* Ap = (tau < 2) ? s1h : s1l;
        const unsigned short* Bp = (tau == 1) ? Gl : Gh;
        const unsigned short* arow = Ap + (size_t)(b * L + l0 + lr) * D + lq * 8;
        const unsigned short* brow = Bp + (size_t)b * DD + (size_t)(n0 + lr) * D + lq * 8;
#pragma unroll
        for (int kk = 0; kk < 256; kk += 32) {
            bf16x8 af[4], bfr[2];
#pragma unroll
            for (int i = 0; i < 4; ++i)
                af[i] = *(const bf16x8*)(arow + (size_t)i * 16 * D + kk);
#pragma unroll
            for (int j = 0; j < 2; ++j)
                bfr[j] = *(const bf16x8*)(brow + (size_t)j * 16 * D + kk);
#pragma unroll
            for (int i = 0; i < 4; ++i)
#pragma unroll
                for (int j = 0; j < 2; ++j)
                    acc[i][j] = __builtin_amdgcn_mfma_f32_16x16x32_bf16(af[i], bfr[j], acc[i][j], 0, 0, 0);
        }
    }
#pragma unroll
    for (int i = 0; i < 4; ++i)
#pragma unroll
        for (int r = 0; r < 4; ++r) {
            int l = l0 + i * 16 + lq * 4 + r;
            float iv = invU[b * L + l];
#pragma unroll
            for (int j = 0; j < 2; ++j)
                mav[(size_t)(b * L + l) * D + n0 + j * 16 + lr] = acc[i][j][r] * iv;
        }
}

// K7: out[row,p] = (sum s1*mav*k2p) * rnv1[row,p] * rsqrt(max(sum mav^2 k2p,eps)).
__global__ __launch_bounds__(256) void k_out(const float* __restrict__ s1,
                                             const float* __restrict__ mav,
                                             const float* __restrict__ kern,
                                             const float* __restrict__ rnv1,
                                             float* __restrict__ out) {
    __shared__ float k2s[P * D];
    int tid = threadIdx.x;
#pragma unroll
    for (int p = 0; p < P; ++p) {
        float v = kern[p * D + tid];
        k2s[p * D + tid] = v * v;
    }
    __syncthreads();

    int w = tid >> 6, lane = tid & 63;
    int row = blockIdx.x * 4 + w;
    int dg = lane & 15, ps = lane >> 4;

    const float* s1p = s1 + (size_t)row * D + dg * 4;
    const float* mvp = mav + (size_t)row * D + dg * 4;
    float4 sm[4], mm[4];
#pragma unroll
    for (int j = 0; j < 4; ++j) {
        float4 sv = *(const float4*)(s1p + j * 64);
        float4 mv = *(const float4*)(mvp + j * 64);
        sm[j].x = sv.x * mv.x; sm[j].y = sv.y * mv.y; sm[j].z = sv.z * mv.z; sm[j].w = sv.w * mv.w;
        mm[j].x = mv.x * mv.x; mm[j].y = mv.y * mv.y; mm[j].z = mv.z * mv.z; mm[j].w = mv.w * mv.w;
    }
#pragma unroll
    for (int tI = 0; tI < 5; ++tI) {
        int p = ps + tI * 4;
        float na = 0.f, nc = 0.f;
#pragma unroll
        for (int j = 0; j < 4; ++j) {
            float4 kv = *(const float4*)&k2s[p * D + j * 64 + dg * 4];
            na += sm[j].x * kv.x + sm[j].y * kv.y + sm[j].z * kv.z + sm[j].w * kv.w;
            nc += mm[j].x * kv.x + mm[j].y * kv.y + mm[j].z * kv.z + mm[j].w * kv.w;
        }
#pragma unroll
        for (int o = 8; o; o >>= 1) {
            na += __shfl_down(na, o, 16);
            nc += __shfl_down(nc, o, 16);
        }
        if (dg == 0) {
            out[(size_t)row * P + p] = na * rnv1[(size_t)row * P + p] *
                                       rsqrtf(fmaxf(nc, EPS));
        }
    }
}

extern "C" void kernel_launch(void* const* d_in, const int* in_sizes, int n_in,
                              void* d_out, int out_size, void* d_ws, size_t ws_size,
                              hipStream_t stream) {
    const float* s1   = (const float*)d_in[0];
    const float* s2   = (const float*)d_in[1];
    const float* kern = (const float*)d_in[2];
    float* out = (float*)d_out;
    float* ws  = (float*)d_ws;

    float* n1    = ws;
    float* invn2 = ws + 16384;
    float* t     = ws + 32768;
    float* invU  = ws + 36864;
    float* rnv1  = ws + 53248;
    unsigned short* s1h = (unsigned short*)(ws + 380928);
    unsigned short* s1l = (unsigned short*)(ws + 2478080);
    unsigned short* ChT = (unsigned short*)(ws + 4575232);
    unsigned short* ClT = (unsigned short*)(ws + 6672384);
    unsigned short* Gh  = (unsigned short*)(ws + 8769536);
    unsigned short* Gl  = (unsigned short*)(ws + 9293824);
    float* Gp  = ws + 9818112;
    float* mav = ws + 18206720;

    hipMemsetAsync(t, 0, (size_t)4096 * sizeof(float), stream);

    k_norms<<<8192, 256, 0, stream>>>(s1, s2, n1, invn2, s1h, s1l);
    k_split2<<<1024, 256, 0, stream>>>(s2, invn2, ChT, ClT, t);
    k_u<<<4096, 256, 0, stream>>>(s1, t, n1, kern, invU, rnv1);
    k_gram_mfma<<<512, 256, 0, stream>>>(ChT, ClT, Gp);
    k_reduceG<<<1024, 256, 0, stream>>>(Gp, Gh, Gl);
    k_mav_mfma<<<512, 256, 0, stream>>>(s1h, s1l, Gh, Gl, invU, mav);
    k_out<<<4096, 256, 0, stream>>>(s1, mav, kern, rnv1, out);
}

// Round 8
// 159.528 us; speedup vs baseline: 1.4988x; 1.4988x over previous
//
#include <hip/hip_runtime.h>
#include <math.h>

#define EPS 1e-7f

constexpr int B = 16, L = 1024, D = 256, P = 20;
constexpr int LD = L * D;     // 262144
constexpr int DD = D * D;     // 65536

typedef __attribute__((ext_vector_type(8))) short bf16x8;
typedef __attribute__((ext_vector_type(4))) float f32x4;

// ---------------------------------------------------------------------------
// ws layout (float slots):
//   n1    @0         16384     fp32 [B*L]
//   invn2 @16384     16384     fp32 [B*L]
//   tp    @32768     65536     fp32 [16][B][D]  t partials (plain stores)
//   invU  @98304     16384     fp32 [B*L]
//   rnv1  @114688    327680    fp32 [B*L][P]
//   s1h   @442368    2097152   bf16 [B*L][D]
//   s1l   @2539520   2097152   bf16 [B*L][D]
//   ChT   @4636672   2097152   bf16 [B][D][L]  (s2*sqrt(invn2), transposed, hi)
//   ClT   @6733824   2097152   bf16 [B][D][L]  (lo)
//   Gh    @8830976   524288    bf16 [B][D][D]
//   Gl    @9355264   524288    bf16 [B][D][D]
//   Gp    @9879552   8388608   fp32 [8][B][D][D]  gram K-split partials
//   mav   @18268160  4194304   fp32 [B*L][D]
// total 22462464 floats = 89.8 MB.  NO global atomics anywhere.
// ---------------------------------------------------------------------------

__device__ inline void bf16split(float x, unsigned short &h, unsigned short &l) {
    union { float f; unsigned u; } a; a.f = x;
    unsigned hu = (a.u + 0x7FFFu + ((a.u >> 16) & 1u)) & 0xFFFF0000u;
    union { unsigned u; float f; } hb; hb.u = hu;
    h = (unsigned short)(hu >> 16);
    float r = x - hb.f;
    union { float f; unsigned u; } c; c.f = r;
    l = (unsigned short)((c.u + 0x7FFFu + ((c.u >> 16) & 1u)) >> 16);
}

// K1: per-row L2 norms; also emits bf16 hi/lo split of s1.
__global__ __launch_bounds__(256) void k_norms(const float* __restrict__ s1,
                                               const float* __restrict__ s2,
                                               float* __restrict__ n1,
                                               float* __restrict__ invn2,
                                               unsigned short* __restrict__ s1h,
                                               unsigned short* __restrict__ s1l) {
    int tid  = threadIdx.x;
    int lane = tid & 63, w = tid >> 6;
    int row  = blockIdx.x * 4 + w;            // 0..32767
    int r    = (row < B * L) ? row : row - B * L;
    const float* src = (row < B * L) ? s1 : s2;
    float4 v = *(const float4*)(src + (size_t)r * D + lane * 4);
    float s = v.x * v.x + v.y * v.y + v.z * v.z + v.w * v.w;
#pragma unroll
    for (int o = 32; o; o >>= 1) s += __shfl_down(s, o);
    if (row < B * L) {
        ushort4 h4, l4;
        bf16split(v.x, h4.x, l4.x);
        bf16split(v.y, h4.y, l4.y);
        bf16split(v.z, h4.z, l4.z);
        bf16split(v.w, h4.w, l4.w);
        *(ushort4*)(s1h + (size_t)r * D + lane * 4) = h4;
        *(ushort4*)(s1l + (size_t)r * D + lane * 4) = l4;
    }
    if (lane == 0) {
        float n = sqrtf(fmaxf(s, EPS));
        if (row < B * L) n1[r] = n;
        else             invn2[r] = 1.0f / n;
    }
}

// K2: t partials, NO atomics.  tp[mc][b][d] = sum_{m in chunk} s2[b,m,d]*invn2[b,m].
// Grid: 16 b x 16 mc (64 m per chunk).
__global__ __launch_bounds__(256) void k_t(const float* __restrict__ s2,
                                           const float* __restrict__ invn2,
                                           float* __restrict__ tp) {
    int b  = blockIdx.x >> 4;
    int mc = blockIdx.x & 15;
    int d  = threadIdx.x;
    const float* sp = s2 + (size_t)b * LD + (size_t)mc * 64 * D + d;
    const float* wp = invn2 + b * L + mc * 64;
    float acc = 0.f;
#pragma unroll 4
    for (int m = 0; m < 64; ++m) acc += sp[(size_t)m * D] * wp[m];
    tp[(size_t)(mc * B + b) * D + d] = acc;
}

// K3: invU[row] = 1/(s1.t + eps*n1), rnv1[row][p] = rsqrt(max(s1^2.k2p, eps)).
// Reduces the 16 t-partials into LDS once per block (block spans a single b).
__global__ __launch_bounds__(256) void k_u(const float* __restrict__ s1,
                                           const float* __restrict__ tp,
                                           const float* __restrict__ n1,
                                           const float* __restrict__ kern,
                                           float* __restrict__ invU,
                                           float* __restrict__ rnv1) {
    __shared__ float k2s[P * D];   // 20 KB
    __shared__ float ts[D];
    int tid = threadIdx.x;
#pragma unroll
    for (int p = 0; p < P; ++p) {
        float v = kern[p * D + tid];
        k2s[p * D + tid] = v * v;
    }
    {
        int b0 = (blockIdx.x * 4) >> 10;      // all 4 rows share b
        float acc = 0.f;
#pragma unroll
        for (int mc = 0; mc < 16; ++mc)
            acc += tp[(size_t)(mc * B + b0) * D + tid];
        ts[tid] = acc;
    }
    __syncthreads();

    int w = tid >> 6, lane = tid & 63;
    int row = blockIdx.x * 4 + w;             // 0..16383
    int dg = lane & 15, ps = lane >> 4;

    float4 sv[4], ss[4];
    float up = 0.f;
#pragma unroll
    for (int j = 0; j < 4; ++j) {
        sv[j] = *(const float4*)(s1 + (size_t)row * D + dg * 4 + j * 64);
        float4 tv = *(const float4*)(ts + dg * 4 + j * 64);
        up += sv[j].x * tv.x + sv[j].y * tv.y + sv[j].z * tv.z + sv[j].w * tv.w;
        ss[j].x = sv[j].x * sv[j].x; ss[j].y = sv[j].y * sv[j].y;
        ss[j].z = sv[j].z * sv[j].z; ss[j].w = sv[j].w * sv[j].w;
    }
#pragma unroll
    for (int o = 8; o; o >>= 1) up += __shfl_down(up, o, 16);
    if (dg == 0 && ps == 0) invU[row] = 1.0f / (up + EPS * n1[row]);
#pragma unroll
    for (int tI = 0; tI < 5; ++tI) {
        int p = ps + tI * 4;
        float nb = 0.f;
#pragma unroll
        for (int j = 0; j < 4; ++j) {
            float4 kv = *(const float4*)&k2s[p * D + j * 64 + dg * 4];
            nb += ss[j].x * kv.x + ss[j].y * kv.y + ss[j].z * kv.z + ss[j].w * kv.w;
        }
#pragma unroll
        for (int o = 8; o; o >>= 1) nb += __shfl_down(nb, o, 16);
        if (dg == 0) rnv1[(size_t)row * P + p] = rsqrtf(fmaxf(nb, EPS));
    }
}

// K4: transpose+split C = s2*sqrt(invn2) -> ChT/ClT [B][D][L] bf16 (K=m contig).
__global__ __launch_bounds__(256) void k_split2(const float* __restrict__ s2,
                                                const float* __restrict__ invn2,
                                                unsigned short* __restrict__ ChT,
                                                unsigned short* __restrict__ ClT) {
    __shared__ float tile[64][65];
    __shared__ float wsh[64];
    int tid = threadIdx.x;
    int b   = blockIdx.x >> 6;
    int rem = blockIdx.x & 63;
    int mt  = rem >> 2, dt = rem & 3;
    int m0  = mt * 64, d0 = dt * 64;
    {
        int r = tid >> 2, cs = (tid & 3) * 16;
        const float* gp = s2 + (size_t)b * LD + (size_t)(m0 + r) * D + d0 + cs;
        float4 v0 = ((const float4*)gp)[0];
        float4 v1 = ((const float4*)gp)[1];
        float4 v2 = ((const float4*)gp)[2];
        float4 v3 = ((const float4*)gp)[3];
        *(float4*)&tile[r][cs]      = v0;
        *(float4*)&tile[r][cs + 4]  = v1;
        *(float4*)&tile[r][cs + 8]  = v2;
        *(float4*)&tile[r][cs + 12] = v3;
        if (tid < 64) wsh[tid] = sqrtf(invn2[b * L + m0 + tid]);
    }
    __syncthreads();
    int dc = tid >> 2, ms = (tid & 3) * 16;
    union { unsigned short us[16]; uint4 q[2]; } pCh, pCl;
#pragma unroll
    for (int k = 0; k < 16; ++k) {
        int m = ms + k;
        float wv = tile[m][dc] * wsh[m];
        bf16split(wv, pCh.us[k], pCl.us[k]);
    }
    size_t o = (size_t)b * LD + (size_t)(d0 + dc) * L + m0 + ms;
    *(uint4*)(ChT + o) = pCh.q[0]; *(uint4*)(ChT + o + 8) = pCh.q[1];
    *(uint4*)(ClT + o) = pCl.q[0]; *(uint4*)(ClT + o + 8) = pCl.q[1];
}

// K5: Gram via MFMA (LDS-staged).  G = Ch'Ch + Ch'Cl + Cl'Ch, K-split x8.
// Block: 128x128 tile, 4 waves 2x2, wave = 64x64 = 4x4 MFMA 16x16x32.
// Grid: 16 b x (2 ti x 2 tj x 8 kc) = 512 -> 2 blocks/CU.
__global__ __launch_bounds__(256) void k_gram_mfma(const unsigned short* __restrict__ ChT,
                                                   const unsigned short* __restrict__ ClT,
                                                   float* __restrict__ Gp) {
    __shared__ short As[128 * 72];
    __shared__ short Bs[128 * 72];
    int tid  = threadIdx.x;
    int b    = blockIdx.x >> 5;
    int rem  = blockIdx.x & 31;
    int kc   = rem & 7;
    int tj   = (rem >> 3) & 1, ti = (rem >> 4) & 1;
    int wave = tid >> 6, lane = tid & 63;
    int wr   = (wave >> 1) * 64, wcc = (wave & 1) * 64;
    int lr   = lane & 15, lq = lane >> 4;
    int srow = tid >> 1, shalf = (tid & 1) * 32;

    f32x4 acc[4][4];
#pragma unroll
    for (int i = 0; i < 4; ++i)
#pragma unroll
        for (int j = 0; j < 4; ++j) acc[i][j] = (f32x4){0.f, 0.f, 0.f, 0.f};

#pragma unroll 1
    for (int tau = 0; tau < 3; ++tau) {
        const unsigned short* Ap = (tau < 2) ? ChT : ClT;
        const unsigned short* Bp = (tau == 1) ? ClT : ChT;
#pragma unroll 1
        for (int kb = 0; kb < 2; ++kb) {
            int koff = kc * 128 + kb * 64 + shalf;
            __syncthreads();
            {
                const unsigned short* ga = Ap + (size_t)b * LD + (size_t)(ti * 128 + srow) * L + koff;
                const unsigned short* gb = Bp + (size_t)b * LD + (size_t)(tj * 128 + srow) * L + koff;
                uint4 a0 = ((const uint4*)ga)[0], a1 = ((const uint4*)ga)[1];
                uint4 a2 = ((const uint4*)ga)[2], a3 = ((const uint4*)ga)[3];
                uint4 b0 = ((const uint4*)gb)[0], b1 = ((const uint4*)gb)[1];
                uint4 b2 = ((const uint4*)gb)[2], b3 = ((const uint4*)gb)[3];
                short* la = &As[srow * 72 + shalf];
                short* lb = &Bs[srow * 72 + shalf];
                ((uint4*)la)[0] = a0; ((uint4*)la)[1] = a1;
                ((uint4*)la)[2] = a2; ((uint4*)la)[3] = a3;
                ((uint4*)lb)[0] = b0; ((uint4*)lb)[1] = b1;
                ((uint4*)lb)[2] = b2; ((uint4*)lb)[3] = b3;
            }
            __syncthreads();
#pragma unroll
            for (int ks = 0; ks < 2; ++ks) {
                bf16x8 af[4], bfr[4];
#pragma unroll
                for (int i = 0; i < 4; ++i)
                    af[i] = *(const bf16x8*)&As[(wr + i * 16 + lr) * 72 + ks * 32 + lq * 8];
#pragma unroll
                for (int j = 0; j < 4; ++j)
                    bfr[j] = *(const bf16x8*)&Bs[(wcc + j * 16 + lr) * 72 + ks * 32 + lq * 8];
#pragma unroll
                for (int i = 0; i < 4; ++i)
#pragma unroll
                    for (int j = 0; j < 4; ++j)
                        acc[i][j] = __builtin_amdgcn_mfma_f32_16x16x32_bf16(af[i], bfr[j], acc[i][j], 0, 0, 0);
            }
        }
    }
    float* gout = Gp + ((size_t)(kc * B + b)) * DD;
#pragma unroll
    for (int i = 0; i < 4; ++i)
#pragma unroll
        for (int r = 0; r < 4; ++r) {
            int row = ti * 128 + wr + i * 16 + lq * 4 + r;
#pragma unroll
            for (int j = 0; j < 4; ++j)
                gout[(size_t)row * D + tj * 128 + wcc + j * 16 + lr] = acc[i][j][r];
        }
}

// K6: reduce 8 gram partials; emit bf16 hi/lo split of G.
__global__ __launch_bounds__(256) void k_reduceG(const float* __restrict__ Gp,
                                                 unsigned short* __restrict__ Gh,
                                                 unsigned short* __restrict__ Gl) {
    size_t i = ((size_t)blockIdx.x * 256 + threadIdx.x) * 4;
    float4 s = *(const float4*)(Gp + i);
#pragma unroll
    for (int kc = 1; kc < 8; ++kc) {
        float4 a = *(const float4*)(Gp + (size_t)kc * B * DD + i);
        s.x += a.x; s.y += a.y; s.z += a.z; s.w += a.w;
    }
    ushort4 h4, l4;
    bf16split(s.x, h4.x, l4.x);
    bf16split(s.y, h4.y, l4.y);
    bf16split(s.z, h4.z, l4.z);
    bf16split(s.w, h4.w, l4.w);
    *(ushort4*)(Gh + i) = h4;
    *(ushort4*)(Gl + i) = l4;
}

// K7: mav = (s1 @ G) * invU via MFMA (LDS-staged).  Block = 64 l x 128 n,
// 4 waves each 64l x 32n (4x2 MFMA).  B rows read from G directly (symmetric).
// Grid: 16 b x 16 lt x 2 nt = 512 -> 2 blocks/CU (27.6 KB LDS).
__global__ __launch_bounds__(256) void k_mav_mfma(const unsigned short* __restrict__ s1h,
                                                  const unsigned short* __restrict__ s1l,
                                                  const unsigned short* __restrict__ Gh,
                                                  const unsigned short* __restrict__ Gl,
                                                  const float* __restrict__ invU,
                                                  float* __restrict__ mav) {
    __shared__ short As[64 * 72];
    __shared__ short Bs[128 * 72];
    int tid  = threadIdx.x;
    int b    = blockIdx.x >> 5;
    int rem  = blockIdx.x & 31;
    int lt   = rem >> 1, nt = rem & 1;
    int l0   = lt * 64, n0 = nt * 128;
    int wave = tid >> 6, lane = tid & 63;
    int wn   = wave * 32;
    int lr   = lane & 15, lq = lane >> 4;
    int arow = tid >> 2, aq = (tid & 3) * 16;      // A: 64 rows x 64 shorts
    int brow = tid >> 1, bhalf = (tid & 1) * 32;   // B: 128 rows x 64 shorts

    f32x4 acc[4][2];
#pragma unroll
    for (int i = 0; i < 4; ++i)
#pragma unroll
        for (int j = 0; j < 2; ++j) acc[i][j] = (f32x4){0.f, 0.f, 0.f, 0.f};

#pragma unroll 1
    for (int tau = 0; tau < 3; ++tau) {
        const unsigned short* Ap = (tau < 2) ? s1h : s1l;
        const unsigned short* Bp = (tau == 1) ? Gl : Gh;
#pragma unroll 1
        for (int kb = 0; kb < 4; ++kb) {
            int koff = kb * 64;
            __syncthreads();
            {
                const unsigned short* ga = Ap + (size_t)(b * L + l0 + arow) * D + koff + aq;
                uint4 a0 = ((const uint4*)ga)[0], a1 = ((const uint4*)ga)[1];
                const unsigned short* gb = Bp + (size_t)b * DD + (size_t)(n0 + brow) * D + koff + bhalf;
                uint4 b0 = ((const uint4*)gb)[0], b1 = ((const uint4*)gb)[1];
                uint4 b2 = ((const uint4*)gb)[2], b3 = ((const uint4*)gb)[3];
                short* la = &As[arow * 72 + aq];
                ((uint4*)la)[0] = a0; ((uint4*)la)[1] = a1;
                short* lb = &Bs[brow * 72 + bhalf];
                ((uint4*)lb)[0] = b0; ((uint4*)lb)[1] = b1;
                ((uint4*)lb)[2] = b2; ((uint4*)lb)[3] = b3;
            }
            __syncthreads();
#pragma unroll
            for (int ks = 0; ks < 2; ++ks) {
                bf16x8 af[4], bfr[2];
#pragma unroll
                for (int i = 0; i < 4; ++i)
                    af[i] = *(const bf16x8*)&As[(i * 16 + lr) * 72 + ks * 32 + lq * 8];
#pragma unroll
                for (int j = 0; j < 2; ++j)
                    bfr[j] = *(const bf16x8*)&Bs[(wn + j * 16 + lr) * 72 + ks * 32 + lq * 8];
#pragma unroll
                for (int i = 0; i < 4; ++i)
#pragma unroll
                    for (int j = 0; j < 2; ++j)
                        acc[i][j] = __builtin_amdgcn_mfma_f32_16x16x32_bf16(af[i], bfr[j], acc[i][j], 0, 0, 0);
            }
        }
    }
#pragma unroll
    for (int i = 0; i < 4; ++i)
#pragma unroll
        for (int r = 0; r < 4; ++r) {
            int l = l0 + i * 16 + lq * 4 + r;
            float iv = invU[b * L + l];
#pragma unroll
            for (int j = 0; j < 2; ++j)
                mav[(size_t)(b * L + l) * D + n0 + wn + j * 16 + lr] = acc[i][j][r] * iv;
        }
}

// K8: out[row,p] = (sum s1*mav*k2p) * rnv1[row,p] * rsqrt(max(sum mav^2 k2p,eps)).
__global__ __launch_bounds__(256) void k_out(const float* __restrict__ s1,
                                             const float* __restrict__ mav,
                                             const float* __restrict__ kern,
                                             const float* __restrict__ rnv1,
                                             float* __restrict__ out) {
    __shared__ float k2s[P * D];
    int tid = threadIdx.x;
#pragma unroll
    for (int p = 0; p < P; ++p) {
        float v = kern[p * D + tid];
        k2s[p * D + tid] = v * v;
    }
    __syncthreads();

    int w = tid >> 6, lane = tid & 63;
    int row = blockIdx.x * 4 + w;
    int dg = lane & 15, ps = lane >> 4;

    const float* s1p = s1 + (size_t)row * D + dg * 4;
    const float* mvp = mav + (size_t)row * D + dg * 4;
    float4 sm[4], mm[4];
#pragma unroll
    for (int j = 0; j < 4; ++j) {
        float4 sv = *(const float4*)(s1p + j * 64);
        float4 mv = *(const float4*)(mvp + j * 64);
        sm[j].x = sv.x * mv.x; sm[j].y = sv.y * mv.y; sm[j].z = sv.z * mv.z; sm[j].w = sv.w * mv.w;
        mm[j].x = mv.x * mv.x; mm[j].y = mv.y * mv.y; mm[j].z = mv.z * mv.z; mm[j].w = mv.w * mv.w;
    }
#pragma unroll
    for (int tI = 0; tI < 5; ++tI) {
        int p = ps + tI * 4;
        float na = 0.f, nc = 0.f;
#pragma unroll
        for (int j = 0; j < 4; ++j) {
            float4 kv = *(const float4*)&k2s[p * D + j * 64 + dg * 4];
            na += sm[j].x * kv.x + sm[j].y * kv.y + sm[j].z * kv.z + sm[j].w * kv.w;
            nc += mm[j].x * kv.x + mm[j].y * kv.y + mm[j].z * kv.z + mm[j].w * kv.w;
        }
#pragma unroll
        for (int o = 8; o; o >>= 1) {
            na += __shfl_down(na, o, 16);
            nc += __shfl_down(nc, o, 16);
        }
        if (dg == 0) {
            out[(size_t)row * P + p] = na * rnv1[(size_t)row * P + p] *
                                       rsqrtf(fmaxf(nc, EPS));
        }
    }
}

extern "C" void kernel_launch(void* const* d_in, const int* in_sizes, int n_in,
                              void* d_out, int out_size, void* d_ws, size_t ws_size,
                              hipStream_t stream) {
    const float* s1   = (const float*)d_in[0];
    const float* s2   = (const float*)d_in[1];
    const float* kern = (const float*)d_in[2];
    float* out = (float*)d_out;
    float* ws  = (float*)d_ws;

    float* n1    = ws;
    float* invn2 = ws + 16384;
    float* tp    = ws + 32768;
    float* invU  = ws + 98304;
    float* rnv1  = ws + 114688;
    unsigned short* s1h = (unsigned short*)(ws + 442368);
    unsigned short* s1l = (unsigned short*)(ws + 2539520);
    unsigned short* ChT = (unsigned short*)(ws + 4636672);
    unsigned short* ClT = (unsigned short*)(ws + 6733824);
    unsigned short* Gh  = (unsigned short*)(ws + 8830976);
    unsigned short* Gl  = (unsigned short*)(ws + 9355264);
    float* Gp  = ws + 9879552;
    float* mav = ws + 18268160;

    k_norms<<<8192, 256, 0, stream>>>(s1, s2, n1, invn2, s1h, s1l);
    k_t<<<256, 256, 0, stream>>>(s2, invn2, tp);
    k_u<<<4096, 256, 0, stream>>>(s1, tp, n1, kern, invU, rnv1);
    k_split2<<<1024, 256, 0, stream>>>(s2, invn2, ChT, ClT);
    k_gram_mfma<<<512, 256, 0, stream>>>(ChT, ClT, Gp);
    k_reduceG<<<1024, 256, 0, stream>>>(Gp, Gh, Gl);
    k_mav_mfma<<<512, 256, 0, stream>>>(s1h, s1l, Gh, Gl, invU, mav);
    k_out<<<4096, 256, 0, stream>>>(s1, mav, kern, rnv1, out);
}

// Round 9
// 149.778 us; speedup vs baseline: 1.5963x; 1.0651x over previous
//
#include <hip/hip_runtime.h>
#include <math.h>

#define EPS 1e-7f

constexpr int B = 16, L = 1024, D = 256, P = 20;
constexpr int LD = L * D;     // 262144
constexpr int DD = D * D;     // 65536

typedef __attribute__((ext_vector_type(8))) short bf16x8;
typedef __attribute__((ext_vector_type(4))) float f32x4;

// ---------------------------------------------------------------------------
// ws layout (float slots).  NO atomics, NO memsets; every buffer fully
// written before read (harness poisons ws with 0xAA each iteration).
//   tp    @0         131072    fp32 [32][B][D]  t partials
//   invU  @131072    16384     fp32 [B*L]
//   s1h   @147456    2097152   bf16 [B*L][D]
//   s1l   @2244608   2097152   bf16 [B*L][D]
//   ChT   @4341760   2097152   bf16 [B][D][L]  (s2*sqrt(invn2), transposed, hi)
//   ClT   @6438912   2097152   bf16 [B][D][L]  (lo)
//   Gh    @8536064   524288    bf16 [B][D][D]
//   Gl    @9060352   524288    bf16 [B][D][D]
//   Gp    @9584640   8388608   fp32 [8][B][D][D]  gram K-split partials
//   mav   @17973248  4194304   fp32 [B*L][D]
// total 22167552 floats = 88.7 MB
// ---------------------------------------------------------------------------

__device__ inline void bf16split(float x, unsigned short &h, unsigned short &l) {
    union { float f; unsigned u; } a; a.f = x;
    unsigned hu = (a.u + 0x7FFFu + ((a.u >> 16) & 1u)) & 0xFFFF0000u;
    union { unsigned u; float f; } hb; hb.u = hu;
    h = (unsigned short)(hu >> 16);
    float r = x - hb.f;
    union { float f; unsigned u; } c; c.f = r;
    l = (unsigned short)((c.u + 0x7FFFu + ((c.u >> 16) & 1u)) >> 16);
}

__device__ inline float b2f(unsigned short u) {
    union { unsigned u; float f; } a; a.u = (unsigned)u << 16; return a.f;
}

// K1: one pass over s2.  Block = 32 full rows (b, m0..m0+31).  Computes
// invn2 locally, emits tp partials (plain stores) and transposed bf16
// hi/lo ChT/ClT.  Grid: 16 b x 32 mt = 512.  LDS 32x257 fp32 (pad->no
// bank conflicts on column reads).
__global__ __launch_bounds__(256) void k_prep2(const float* __restrict__ s2,
                                               float* __restrict__ tp,
                                               unsigned short* __restrict__ ChT,
                                               unsigned short* __restrict__ ClT) {
    __shared__ float tile[32][257];
    __shared__ float wiv[32];   // invn2 = 1/norm
    __shared__ float wsq[32];   // sqrt(invn2)
    int tid = threadIdx.x;
    int b   = blockIdx.x >> 5, mt = blockIdx.x & 31;
    int m0  = mt * 32;
    {
        int r = tid >> 3, c0 = (tid & 7) * 32;
        const float* gp = s2 + (size_t)b * LD + (size_t)(m0 + r) * D + c0;
        float4 v[8];
#pragma unroll
        for (int q = 0; q < 8; ++q) v[q] = ((const float4*)gp)[q];
#pragma unroll
        for (int q = 0; q < 8; ++q) *(float4*)&tile[r][c0 + q * 4] = v[q];
    }
    __syncthreads();
    {
        int r = tid >> 3, seg = tid & 7;
        float s = 0.f;
#pragma unroll
        for (int k = 0; k < 32; ++k) { float v = tile[r][seg * 32 + k]; s += v * v; }
#pragma unroll
        for (int o = 4; o; o >>= 1) s += __shfl_down(s, o, 8);
        if (seg == 0) {
            float iv = 1.0f / sqrtf(fmaxf(s, EPS));
            wiv[r] = iv;
            wsq[r] = sqrtf(iv);
        }
    }
    __syncthreads();
    {
        int dc = tid;                          // d-column 0..255
        float tpart = 0.f;
        union { unsigned short us[32]; uint4 q[4]; } ph, pl;
#pragma unroll
        for (int m = 0; m < 32; ++m) {
            float v = tile[m][dc];
            tpart += v * wiv[m];
            float wv = v * wsq[m];
            bf16split(wv, ph.us[m], pl.us[m]);
        }
        tp[(size_t)(mt * B + b) * D + dc] = tpart;
        size_t o = (size_t)b * LD + (size_t)dc * L + m0;
        *(uint4*)(ChT + o)      = ph.q[0]; *(uint4*)(ChT + o + 8)  = ph.q[1];
        *(uint4*)(ChT + o + 16) = ph.q[2]; *(uint4*)(ChT + o + 24) = ph.q[3];
        *(uint4*)(ClT + o)      = pl.q[0]; *(uint4*)(ClT + o + 8)  = pl.q[1];
        *(uint4*)(ClT + o + 16) = pl.q[2]; *(uint4*)(ClT + o + 24) = pl.q[3];
    }
}

// K2: one pass over s1.  Reduces the 32 t-partials into LDS, computes
// U = s1.t and n1 inline, writes invU = 1/(U + eps*n1) and the bf16 hi/lo
// split of s1.  One wave per row; grid 4096.
__global__ __launch_bounds__(256) void k_u(const float* __restrict__ s1,
                                           const float* __restrict__ tp,
                                           float* __restrict__ invU,
                                           unsigned short* __restrict__ s1h,
                                           unsigned short* __restrict__ s1l) {
    __shared__ float ts[D];
    int tid = threadIdx.x;
    {
        int b0 = (blockIdx.x * 4) >> 10;      // all 4 rows share b
        float acc = 0.f;
#pragma unroll
        for (int mc = 0; mc < 32; ++mc)
            acc += tp[(size_t)(mc * B + b0) * D + tid];
        ts[tid] = acc;
    }
    __syncthreads();

    int w = tid >> 6, lane = tid & 63;
    int row = blockIdx.x * 4 + w;             // 0..16383
    int dg = lane & 15;

    float4 sv[4];
    float up = 0.f, sq = 0.f;
#pragma unroll
    for (int j = 0; j < 4; ++j) {
        sv[j] = *(const float4*)(s1 + (size_t)row * D + dg * 4 + j * 64);
        float4 tv = *(const float4*)(ts + dg * 4 + j * 64);
        up += sv[j].x * tv.x + sv[j].y * tv.y + sv[j].z * tv.z + sv[j].w * tv.w;
        sq += sv[j].x * sv[j].x + sv[j].y * sv[j].y + sv[j].z * sv[j].z + sv[j].w * sv[j].w;
    }
#pragma unroll
    for (int o = 8; o; o >>= 1) {
        up += __shfl_down(up, o, 16);
        sq += __shfl_down(sq, o, 16);
    }
    if (lane == 0) {
        float n1v = sqrtf(fmaxf(sq, EPS));
        invU[row] = 1.0f / (up + EPS * n1v);
    }
#pragma unroll
    for (int j = 0; j < 4; ++j) {
        ushort4 h4, l4;
        bf16split(sv[j].x, h4.x, l4.x);
        bf16split(sv[j].y, h4.y, l4.y);
        bf16split(sv[j].z, h4.z, l4.z);
        bf16split(sv[j].w, h4.w, l4.w);
        *(ushort4*)(s1h + (size_t)row * D + dg * 4 + j * 64) = h4;
        *(ushort4*)(s1l + (size_t)row * D + dg * 4 + j * 64) = l4;
    }
}

// K3: Gram via MFMA (LDS-staged).  G = Ch'Ch + Ch'Cl + Cl'Ch, K-split x8.
// Block: 128x128 tile, 4 waves 2x2, wave = 64x64 = 4x4 MFMA 16x16x32.
// Grid: 16 b x (2 ti x 2 tj x 8 kc) = 512 -> 2 blocks/CU.
__global__ __launch_bounds__(256) void k_gram_mfma(const unsigned short* __restrict__ ChT,
                                                   const unsigned short* __restrict__ ClT,
                                                   float* __restrict__ Gp) {
    __shared__ short As[128 * 72];
    __shared__ short Bs[128 * 72];
    int tid  = threadIdx.x;
    int b    = blockIdx.x >> 5;
    int rem  = blockIdx.x & 31;
    int kc   = rem & 7;
    int tj   = (rem >> 3) & 1, ti = (rem >> 4) & 1;
    int wave = tid >> 6, lane = tid & 63;
    int wr   = (wave >> 1) * 64, wcc = (wave & 1) * 64;
    int lr   = lane & 15, lq = lane >> 4;
    int srow = tid >> 1, shalf = (tid & 1) * 32;

    f32x4 acc[4][4];
#pragma unroll
    for (int i = 0; i < 4; ++i)
#pragma unroll
        for (int j = 0; j < 4; ++j) acc[i][j] = (f32x4){0.f, 0.f, 0.f, 0.f};

#pragma unroll 1
    for (int tau = 0; tau < 3; ++tau) {
        const unsigned short* Ap = (tau < 2) ? ChT : ClT;
        const unsigned short* Bp = (tau == 1) ? ClT : ChT;
#pragma unroll 1
        for (int kb = 0; kb < 2; ++kb) {
            int koff = kc * 128 + kb * 64 + shalf;
            __syncthreads();
            {
                const unsigned short* ga = Ap + (size_t)b * LD + (size_t)(ti * 128 + srow) * L + koff;
                const unsigned short* gb = Bp + (size_t)b * LD + (size_t)(tj * 128 + srow) * L + koff;
                uint4 a0 = ((const uint4*)ga)[0], a1 = ((const uint4*)ga)[1];
                uint4 a2 = ((const uint4*)ga)[2], a3 = ((const uint4*)ga)[3];
                uint4 b0 = ((const uint4*)gb)[0], b1 = ((const uint4*)gb)[1];
                uint4 b2 = ((const uint4*)gb)[2], b3 = ((const uint4*)gb)[3];
                short* la = &As[srow * 72 + shalf];
                short* lb = &Bs[srow * 72 + shalf];
                ((uint4*)la)[0] = a0; ((uint4*)la)[1] = a1;
                ((uint4*)la)[2] = a2; ((uint4*)la)[3] = a3;
                ((uint4*)lb)[0] = b0; ((uint4*)lb)[1] = b1;
                ((uint4*)lb)[2] = b2; ((uint4*)lb)[3] = b3;
            }
            __syncthreads();
#pragma unroll
            for (int ks = 0; ks < 2; ++ks) {
                bf16x8 af[4], bfr[4];
#pragma unroll
                for (int i = 0; i < 4; ++i)
                    af[i] = *(const bf16x8*)&As[(wr + i * 16 + lr) * 72 + ks * 32 + lq * 8];
#pragma unroll
                for (int j = 0; j < 4; ++j)
                    bfr[j] = *(const bf16x8*)&Bs[(wcc + j * 16 + lr) * 72 + ks * 32 + lq * 8];
#pragma unroll
                for (int i = 0; i < 4; ++i)
#pragma unroll
                    for (int j = 0; j < 4; ++j)
                        acc[i][j] = __builtin_amdgcn_mfma_f32_16x16x32_bf16(af[i], bfr[j], acc[i][j], 0, 0, 0);
            }
        }
    }
    float* gout = Gp + ((size_t)(kc * B + b)) * DD;
#pragma unroll
    for (int i = 0; i < 4; ++i)
#pragma unroll
        for (int r = 0; r < 4; ++r) {
            int row = ti * 128 + wr + i * 16 + lq * 4 + r;
#pragma unroll
            for (int j = 0; j < 4; ++j)
                gout[(size_t)row * D + tj * 128 + wcc + j * 16 + lr] = acc[i][j][r];
        }
}

// K4: reduce 8 gram partials; emit bf16 hi/lo split of G.
__global__ __launch_bounds__(256) void k_reduceG(const float* __restrict__ Gp,
                                                 unsigned short* __restrict__ Gh,
                                                 unsigned short* __restrict__ Gl) {
    size_t i = ((size_t)blockIdx.x * 256 + threadIdx.x) * 4;
    float4 s = *(const float4*)(Gp + i);
#pragma unroll
    for (int kc = 1; kc < 8; ++kc) {
        float4 a = *(const float4*)(Gp + (size_t)kc * B * DD + i);
        s.x += a.x; s.y += a.y; s.z += a.z; s.w += a.w;
    }
    ushort4 h4, l4;
    bf16split(s.x, h4.x, l4.x);
    bf16split(s.y, h4.y, l4.y);
    bf16split(s.z, h4.z, l4.z);
    bf16split(s.w, h4.w, l4.w);
    *(ushort4*)(Gh + i) = h4;
    *(ushort4*)(Gl + i) = l4;
}

// K5: mav = (s1 @ G) * invU via MFMA (LDS-staged).  Block = 64 l x 128 n,
// 4 waves each 64l x 32n (4x2 MFMA).  Grid: 16 b x 16 lt x 2 nt = 512.
__global__ __launch_bounds__(256) void k_mav_mfma(const unsigned short* __restrict__ s1h,
                                                  const unsigned short* __restrict__ s1l,
                                                  const unsigned short* __restrict__ Gh,
                                                  const unsigned short* __restrict__ Gl,
                                                  const float* __restrict__ invU,
                                                  float* __restrict__ mav) {
    __shared__ short As[64 * 72];
    __shared__ short Bs[128 * 72];
    int tid  = threadIdx.x;
    int b    = blockIdx.x >> 5;
    int rem  = blockIdx.x & 31;
    int lt   = rem >> 1, nt = rem & 1;
    int l0   = lt * 64, n0 = nt * 128;
    int wave = tid >> 6, lane = tid & 63;
    int wn   = wave * 32;
    int lr   = lane & 15, lq = lane >> 4;
    int arow = tid >> 2, aq = (tid & 3) * 16;      // A: 64 rows x 64 shorts
    int brow = tid >> 1, bhalf = (tid & 1) * 32;   // B: 128 rows x 64 shorts

    f32x4 acc[4][2];
#pragma unroll
    for (int i = 0; i < 4; ++i)
#pragma unroll
        for (int j = 0; j < 2; ++j) acc[i][j] = (f32x4){0.f, 0.f, 0.f, 0.f};

#pragma unroll 1
    for (int tau = 0; tau < 3; ++tau) {
        const unsigned short* Ap = (tau < 2) ? s1h : s1l;
        const unsigned short* Bp = (tau == 1) ? Gl : Gh;
#pragma unroll 1
        for (int kb = 0; kb < 4; ++kb) {
            int koff = kb * 64;
            __syncthreads();
            {
                const unsigned short* ga = Ap + (size_t)(b * L + l0 + arow) * D + koff + aq;
                uint4 a0 = ((const uint4*)ga)[0], a1 = ((const uint4*)ga)[1];
                const unsigned short* gb = Bp + (size_t)b * DD + (size_t)(n0 + brow) * D + koff + bhalf;
                uint4 b0 = ((const uint4*)gb)[0], b1 = ((const uint4*)gb)[1];
                uint4 b2 = ((const uint4*)gb)[2], b3 = ((const uint4*)gb)[3];
                short* la = &As[arow * 72 + aq];
                ((uint4*)la)[0] = a0; ((uint4*)la)[1] = a1;
                short* lb = &Bs[brow * 72 + bhalf];
                ((uint4*)lb)[0] = b0; ((uint4*)lb)[1] = b1;
                ((uint4*)lb)[2] = b2; ((uint4*)lb)[3] = b3;
            }
            __syncthreads();
#pragma unroll
            for (int ks = 0; ks < 2; ++ks) {
                bf16x8 af[4], bfr[2];
#pragma unroll
                for (int i = 0; i < 4; ++i)
                    af[i] = *(const bf16x8*)&As[(i * 16 + lr) * 72 + ks * 32 + lq * 8];
#pragma unroll
                for (int j = 0; j < 2; ++j)
                    bfr[j] = *(const bf16x8*)&Bs[(wn + j * 16 + lr) * 72 + ks * 32 + lq * 8];
#pragma unroll
                for (int i = 0; i < 4; ++i)
#pragma unroll
                    for (int j = 0; j < 2; ++j)
                        acc[i][j] = __builtin_amdgcn_mfma_f32_16x16x32_bf16(af[i], bfr[j], acc[i][j], 0, 0, 0);
            }
        }
    }
#pragma unroll
    for (int i = 0; i < 4; ++i)
#pragma unroll
        for (int r = 0; r < 4; ++r) {
            int l = l0 + i * 16 + lq * 4 + r;
            float iv = invU[b * L + l];
#pragma unroll
            for (int j = 0; j < 2; ++j)
                mav[(size_t)(b * L + l) * D + n0 + wn + j * 16 + lr] = acc[i][j][r] * iv;
        }
}

// K6: out[row,p] = num / nv1 / nv2.  s1 reconstructed from s1h+s1l (exact to
// ~1e-5 rel); all three dot products computed here (rnv1 buffer eliminated).
__global__ __launch_bounds__(256) void k_out(const unsigned short* __restrict__ s1h,
                                             const unsigned short* __restrict__ s1l,
                                             const float* __restrict__ mav,
                                             const float* __restrict__ kern,
                                             float* __restrict__ out) {
    __shared__ float k2s[P * D];
    int tid = threadIdx.x;
#pragma unroll
    for (int p = 0; p < P; ++p) {
        float v = kern[p * D + tid];
        k2s[p * D + tid] = v * v;
    }
    __syncthreads();

    int w = tid >> 6, lane = tid & 63;
    int row = blockIdx.x * 4 + w;
    int dg = lane & 15, ps = lane >> 4;

    float4 sm[4], ss[4], mm[4];
#pragma unroll
    for (int j = 0; j < 4; ++j) {
        ushort4 h4 = *(const ushort4*)(s1h + (size_t)row * D + dg * 4 + j * 64);
        ushort4 l4 = *(const ushort4*)(s1l + (size_t)row * D + dg * 4 + j * 64);
        float4 sv;
        sv.x = b2f(h4.x) + b2f(l4.x);
        sv.y = b2f(h4.y) + b2f(l4.y);
        sv.z = b2f(h4.z) + b2f(l4.z);
        sv.w = b2f(h4.w) + b2f(l4.w);
        float4 mv = *(const float4*)(mav + (size_t)row * D + dg * 4 + j * 64);
        sm[j].x = sv.x * mv.x; sm[j].y = sv.y * mv.y; sm[j].z = sv.z * mv.z; sm[j].w = sv.w * mv.w;
        ss[j].x = sv.x * sv.x; ss[j].y = sv.y * sv.y; ss[j].z = sv.z * sv.z; ss[j].w = sv.w * sv.w;
        mm[j].x = mv.x * mv.x; mm[j].y = mv.y * mv.y; mm[j].z = mv.z * mv.z; mm[j].w = mv.w * mv.w;
    }
#pragma unroll
    for (int tI = 0; tI < 5; ++tI) {
        int p = ps + tI * 4;
        float na = 0.f, nb = 0.f, nc = 0.f;
#pragma unroll
        for (int j = 0; j < 4; ++j) {
            float4 kv = *(const float4*)&k2s[p * D + j * 64 + dg * 4];
            na += sm[j].x * kv.x + sm[j].y * kv.y + sm[j].z * kv.z + sm[j].w * kv.w;
            nb += ss[j].x * kv.x + ss[j].y * kv.y + ss[j].z * kv.z + ss[j].w * kv.w;
            nc += mm[j].x * kv.x + mm[j].y * kv.y + mm[j].z * kv.z + mm[j].w * kv.w;
        }
#pragma unroll
        for (int o = 8; o; o >>= 1) {
            na += __shfl_down(na, o, 16);
            nb += __shfl_down(nb, o, 16);
            nc += __shfl_down(nc, o, 16);
        }
        if (dg == 0) {
            out[(size_t)row * P + p] = na * rsqrtf(fmaxf(nb, EPS)) *
                                       rsqrtf(fmaxf(nc, EPS));
        }
    }
}

extern "C" void kernel_launch(void* const* d_in, const int* in_sizes, int n_in,
                              void* d_out, int out_size, void* d_ws, size_t ws_size,
                              hipStream_t stream) {
    const float* s1   = (const float*)d_in[0];
    const float* s2   = (const float*)d_in[1];
    const float* kern = (const float*)d_in[2];
    float* out = (float*)d_out;
    float* ws  = (float*)d_ws;

    float* tp   = ws;
    float* invU = ws + 131072;
    unsigned short* s1h = (unsigned short*)(ws + 147456);
    unsigned short* s1l = (unsigned short*)(ws + 2244608);
    unsigned short* ChT = (unsigned short*)(ws + 4341760);
    unsigned short* ClT = (unsigned short*)(ws + 6438912);
    unsigned short* Gh  = (unsigned short*)(ws + 8536064);
    unsigned short* Gl  = (unsigned short*)(ws + 9060352);
    float* Gp  = ws + 9584640;
    float* mav = ws + 17973248;

    k_prep2<<<512, 256, 0, stream>>>(s2, tp, ChT, ClT);
    k_u<<<4096, 256, 0, stream>>>(s1, tp, invU, s1h, s1l);
    k_gram_mfma<<<512, 256, 0, stream>>>(ChT, ClT, Gp);
    k_reduceG<<<1024, 256, 0, stream>>>(Gp, Gh, Gl);
    k_mav_mfma<<<512, 256, 0, stream>>>(s1h, s1l, Gh, Gl, invU, mav);
    k_out<<<4096, 256, 0, stream>>>(s1h, s1l, mav, kern, out);
}

// Round 10
// 148.551 us; speedup vs baseline: 1.6095x; 1.0083x over previous
//
#include <hip/hip_runtime.h>
#include <math.h>

#define EPS 1e-7f

constexpr int B = 16, L = 1024, D = 256, P = 20;
constexpr int LD = L * D;     // 262144
constexpr int DD = D * D;     // 65536

typedef __attribute__((ext_vector_type(8))) short bf16x8;
typedef __attribute__((ext_vector_type(4))) float f32x4;

// ---------------------------------------------------------------------------
// ws layout (float slots).  NO atomics, NO memsets.
//   tp    @0         131072    fp32 [32][B][D]  t partials
//   invU  @131072    16384     fp32 [B*L]
//   s1h   @147456    2097152   bf16 [B*L][D]
//   s1l   @2244608   2097152   bf16 [B*L][D]
//   ChT   @4341760   2097152   bf16 [B][D][L]  (s2*sqrt(invn2), transposed, hi)
//   ClT   @6438912   2097152   bf16 [B][D][L]  (lo)
//   Gh    @8536064   524288    bf16 [B][D][D]
//   Gl    @9060352   524288    bf16 [B][D][D]
//   Gp    @9584640   4194304   fp32 [4][B][D][D]  gram K-split partials
//   mavb  @13778944  2097152   bf16 [B*L][D]
// total 15876096 floats = 63.5 MB
// ---------------------------------------------------------------------------

__device__ inline void bf16split(float x, unsigned short &h, unsigned short &l) {
    union { float f; unsigned u; } a; a.f = x;
    unsigned hu = (a.u + 0x7FFFu + ((a.u >> 16) & 1u)) & 0xFFFF0000u;
    union { unsigned u; float f; } hb; hb.u = hu;
    h = (unsigned short)(hu >> 16);
    float r = x - hb.f;
    union { float f; unsigned u; } c; c.f = r;
    l = (unsigned short)((c.u + 0x7FFFu + ((c.u >> 16) & 1u)) >> 16);
}

__device__ inline unsigned short f2b(float x) {
    union { float f; unsigned u; } a; a.f = x;
    return (unsigned short)((a.u + 0x7FFFu + ((a.u >> 16) & 1u)) >> 16);
}

__device__ inline float b2f(unsigned short u) {
    union { unsigned u; float f; } a; a.u = (unsigned)u << 16; return a.f;
}

// K1: one pass over s2.  Block = 32 full rows (b, m0..m0+31).  Computes
// invn2 locally, emits tp partials (plain stores) and transposed bf16
// hi/lo ChT/ClT.  Grid: 16 b x 32 mt = 512.
__global__ __launch_bounds__(256) void k_prep2(const float* __restrict__ s2,
                                               float* __restrict__ tp,
                                               unsigned short* __restrict__ ChT,
                                               unsigned short* __restrict__ ClT) {
    __shared__ float tile[32][257];
    __shared__ float wiv[32];   // invn2 = 1/norm
    __shared__ float wsq[32];   // sqrt(invn2)
    int tid = threadIdx.x;
    int b   = blockIdx.x >> 5, mt = blockIdx.x & 31;
    int m0  = mt * 32;
    {
        int r = tid >> 3, c0 = (tid & 7) * 32;
        const float* gp = s2 + (size_t)b * LD + (size_t)(m0 + r) * D + c0;
        float4 v[8];
#pragma unroll
        for (int q = 0; q < 8; ++q) v[q] = ((const float4*)gp)[q];
#pragma unroll
        for (int q = 0; q < 8; ++q) *(float4*)&tile[r][c0 + q * 4] = v[q];
    }
    __syncthreads();
    {
        int r = tid >> 3, seg = tid & 7;
        float s = 0.f;
#pragma unroll
        for (int k = 0; k < 32; ++k) { float v = tile[r][seg * 32 + k]; s += v * v; }
#pragma unroll
        for (int o = 4; o; o >>= 1) s += __shfl_down(s, o, 8);
        if (seg == 0) {
            float iv = 1.0f / sqrtf(fmaxf(s, EPS));
            wiv[r] = iv;
            wsq[r] = sqrtf(iv);
        }
    }
    __syncthreads();
    {
        int dc = tid;                          // d-column 0..255
        float tpart = 0.f;
        union { unsigned short us[32]; uint4 q[4]; } ph, pl;
#pragma unroll
        for (int m = 0; m < 32; ++m) {
            float v = tile[m][dc];
            tpart += v * wiv[m];
            float wv = v * wsq[m];
            bf16split(wv, ph.us[m], pl.us[m]);
        }
        tp[(size_t)(mt * B + b) * D + dc] = tpart;
        size_t o = (size_t)b * LD + (size_t)dc * L + m0;
        *(uint4*)(ChT + o)      = ph.q[0]; *(uint4*)(ChT + o + 8)  = ph.q[1];
        *(uint4*)(ChT + o + 16) = ph.q[2]; *(uint4*)(ChT + o + 24) = ph.q[3];
        *(uint4*)(ClT + o)      = pl.q[0]; *(uint4*)(ClT + o + 8)  = pl.q[1];
        *(uint4*)(ClT + o + 16) = pl.q[2]; *(uint4*)(ClT + o + 24) = pl.q[3];
    }
}

// K2: one pass over s1.  Reduces t-partials, computes invU inline, writes
// bf16 hi/lo split of s1.  One wave per row; grid 4096.
__global__ __launch_bounds__(256) void k_u(const float* __restrict__ s1,
                                           const float* __restrict__ tp,
                                           float* __restrict__ invU,
                                           unsigned short* __restrict__ s1h,
                                           unsigned short* __restrict__ s1l) {
    __shared__ float ts[D];
    int tid = threadIdx.x;
    {
        int b0 = (blockIdx.x * 4) >> 10;      // all 4 rows share b
        float acc = 0.f;
#pragma unroll
        for (int mc = 0; mc < 32; ++mc)
            acc += tp[(size_t)(mc * B + b0) * D + tid];
        ts[tid] = acc;
    }
    __syncthreads();

    int w = tid >> 6, lane = tid & 63;
    int row = blockIdx.x * 4 + w;             // 0..16383
    int dg = lane & 15;

    float4 sv[4];
    float up = 0.f, sq = 0.f;
#pragma unroll
    for (int j = 0; j < 4; ++j) {
        sv[j] = *(const float4*)(s1 + (size_t)row * D + dg * 4 + j * 64);
        float4 tv = *(const float4*)(ts + dg * 4 + j * 64);
        up += sv[j].x * tv.x + sv[j].y * tv.y + sv[j].z * tv.z + sv[j].w * tv.w;
        sq += sv[j].x * sv[j].x + sv[j].y * sv[j].y + sv[j].z * sv[j].z + sv[j].w * sv[j].w;
    }
#pragma unroll
    for (int o = 8; o; o >>= 1) {
        up += __shfl_down(up, o, 16);
        sq += __shfl_down(sq, o, 16);
    }
    if (lane == 0) {
        float n1v = sqrtf(fmaxf(sq, EPS));
        invU[row] = 1.0f / (up + EPS * n1v);
    }
#pragma unroll
    for (int j = 0; j < 4; ++j) {
        ushort4 h4, l4;
        bf16split(sv[j].x, h4.x, l4.x);
        bf16split(sv[j].y, h4.y, l4.y);
        bf16split(sv[j].z, h4.z, l4.z);
        bf16split(sv[j].w, h4.w, l4.w);
        *(ushort4*)(s1h + (size_t)row * D + dg * 4 + j * 64) = h4;
        *(ushort4*)(s1l + (size_t)row * D + dg * 4 + j * 64) = l4;
    }
}

// K3: Gram via MFMA.  G = Ch'Ch + Ch'Cl + Cl'Ch, K-split x4 (256 m each).
// Block: 128(i) x 64(j) tile, 4 waves 2x2 (64x32 each, 4x2 MFMA 16x16x32).
// Grid: 16 b x (2 ti x 4 tj x 4 kc) = 512 -> 2 blocks/CU, 27.6 KB LDS.
__global__ __launch_bounds__(256) void k_gram_mfma(const unsigned short* __restrict__ ChT,
                                                   const unsigned short* __restrict__ ClT,
                                                   float* __restrict__ Gp) {
    __shared__ short As[128 * 72];
    __shared__ short Bs[64 * 72];
    int tid  = threadIdx.x;
    int b    = blockIdx.x >> 5;
    int rem  = blockIdx.x & 31;
    int ti   = rem >> 4;               // 0..1
    int tj   = (rem >> 2) & 3;         // 0..3
    int kc   = rem & 3;                // 0..3
    int wave = tid >> 6, lane = tid & 63;
    int wr   = (wave >> 1) * 64, wcc = (wave & 1) * 32;
    int lr   = lane & 15, lq = lane >> 4;
    int arow = tid >> 1, ahalf = (tid & 1) * 32;   // A: 128 rows, 2 thr/row
    int brow = tid >> 2, bq = (tid & 3) * 16;      // B: 64 rows, 4 thr/row

    f32x4 acc[4][2];
#pragma unroll
    for (int i = 0; i < 4; ++i)
#pragma unroll
        for (int j = 0; j < 2; ++j) acc[i][j] = (f32x4){0.f, 0.f, 0.f, 0.f};

#pragma unroll 1
    for (int tau = 0; tau < 3; ++tau) {
        const unsigned short* Ap = (tau < 2) ? ChT : ClT;
        const unsigned short* Bp = (tau == 1) ? ClT : ChT;
#pragma unroll 1
        for (int kb = 0; kb < 4; ++kb) {
            int koff = kc * 256 + kb * 64;
            __syncthreads();
            {
                const unsigned short* ga = Ap + (size_t)b * LD + (size_t)(ti * 128 + arow) * L + koff + ahalf;
                uint4 a0 = ((const uint4*)ga)[0], a1 = ((const uint4*)ga)[1];
                uint4 a2 = ((const uint4*)ga)[2], a3 = ((const uint4*)ga)[3];
                const unsigned short* gb = Bp + (size_t)b * LD + (size_t)(tj * 64 + brow) * L + koff + bq;
                uint4 b0 = ((const uint4*)gb)[0], b1 = ((const uint4*)gb)[1];
                short* la = &As[arow * 72 + ahalf];
                ((uint4*)la)[0] = a0; ((uint4*)la)[1] = a1;
                ((uint4*)la)[2] = a2; ((uint4*)la)[3] = a3;
                short* lb = &Bs[brow * 72 + bq];
                ((uint4*)lb)[0] = b0; ((uint4*)lb)[1] = b1;
            }
            __syncthreads();
#pragma unroll
            for (int ks = 0; ks < 2; ++ks) {
                bf16x8 af[4], bfr[2];
#pragma unroll
                for (int i = 0; i < 4; ++i)
                    af[i] = *(const bf16x8*)&As[(wr + i * 16 + lr) * 72 + ks * 32 + lq * 8];
#pragma unroll
                for (int j = 0; j < 2; ++j)
                    bfr[j] = *(const bf16x8*)&Bs[(wcc + j * 16 + lr) * 72 + ks * 32 + lq * 8];
#pragma unroll
                for (int i = 0; i < 4; ++i)
#pragma unroll
                    for (int j = 0; j < 2; ++j)
                        acc[i][j] = __builtin_amdgcn_mfma_f32_16x16x32_bf16(af[i], bfr[j], acc[i][j], 0, 0, 0);
            }
        }
    }
    float* gout = Gp + ((size_t)(kc * B + b)) * DD;
#pragma unroll
    for (int i = 0; i < 4; ++i)
#pragma unroll
        for (int r = 0; r < 4; ++r) {
            int row = ti * 128 + wr + i * 16 + lq * 4 + r;
#pragma unroll
            for (int j = 0; j < 2; ++j)
                gout[(size_t)row * D + tj * 64 + wcc + j * 16 + lr] = acc[i][j][r];
        }
}

// K4: reduce 4 gram partials; emit bf16 hi/lo split of G.
__global__ __launch_bounds__(256) void k_reduceG(const float* __restrict__ Gp,
                                                 unsigned short* __restrict__ Gh,
                                                 unsigned short* __restrict__ Gl) {
    size_t i = ((size_t)blockIdx.x * 256 + threadIdx.x) * 4;
    float4 s = *(const float4*)(Gp + i);
#pragma unroll
    for (int kc = 1; kc < 4; ++kc) {
        float4 a = *(const float4*)(Gp + (size_t)kc * B * DD + i);
        s.x += a.x; s.y += a.y; s.z += a.z; s.w += a.w;
    }
    ushort4 h4, l4;
    bf16split(s.x, h4.x, l4.x);
    bf16split(s.y, h4.y, l4.y);
    bf16split(s.z, h4.z, l4.z);
    bf16split(s.w, h4.w, l4.w);
    *(ushort4*)(Gh + i) = h4;
    *(ushort4*)(Gl + i) = l4;
}

// K5: mavb = bf16((s1 @ G) * invU) via MFMA.  Block = 64 l x 128 n,
// 4 waves each 64l x 32n (4x2 MFMA).  Grid: 16 b x 16 lt x 2 nt = 512.
// (out = num/nv1/nv2 is scale-invariant in mav and each dot averages 256
//  independently-rounded elements, so bf16 mav adds only ~1e-4..1e-3.)
__global__ __launch_bounds__(256) void k_mav_mfma(const unsigned short* __restrict__ s1h,
                                                  const unsigned short* __restrict__ s1l,
                                                  const unsigned short* __restrict__ Gh,
                                                  const unsigned short* __restrict__ Gl,
                                                  const float* __restrict__ invU,
                                                  unsigned short* __restrict__ mavb) {
    __shared__ short As[64 * 72];
    __shared__ short Bs[128 * 72];
    int tid  = threadIdx.x;
    int b    = blockIdx.x >> 5;
    int rem  = blockIdx.x & 31;
    int lt   = rem >> 1, nt = rem & 1;
    int l0   = lt * 64, n0 = nt * 128;
    int wave = tid >> 6, lane = tid & 63;
    int wn   = wave * 32;
    int lr   = lane & 15, lq = lane >> 4;
    int arow = tid >> 2, aq = (tid & 3) * 16;      // A: 64 rows x 64 shorts
    int brow = tid >> 1, bhalf = (tid & 1) * 32;   // B: 128 rows x 64 shorts

    f32x4 acc[4][2];
#pragma unroll
    for (int i = 0; i < 4; ++i)
#pragma unroll
        for (int j = 0; j < 2; ++j) acc[i][j] = (f32x4){0.f, 0.f, 0.f, 0.f};

#pragma unroll 1
    for (int tau = 0; tau < 3; ++tau) {
        const unsigned short* Ap = (tau < 2) ? s1h : s1l;
        const unsigned short* Bp = (tau == 1) ? Gl : Gh;
#pragma unroll 1
        for (int kb = 0; kb < 4; ++kb) {
            int koff = kb * 64;
            __syncthreads();
            {
                const unsigned short* ga = Ap + (size_t)(b * L + l0 + arow) * D + koff + aq;
                uint4 a0 = ((const uint4*)ga)[0], a1 = ((const uint4*)ga)[1];
                const unsigned short* gb = Bp + (size_t)b * DD + (size_t)(n0 + brow) * D + koff + bhalf;
                uint4 b0 = ((const uint4*)gb)[0], b1 = ((const uint4*)gb)[1];
                uint4 b2 = ((const uint4*)gb)[2], b3 = ((const uint4*)gb)[3];
                short* la = &As[arow * 72 + aq];
                ((uint4*)la)[0] = a0; ((uint4*)la)[1] = a1;
                short* lb = &Bs[brow * 72 + bhalf];
                ((uint4*)lb)[0] = b0; ((uint4*)lb)[1] = b1;
                ((uint4*)lb)[2] = b2; ((uint4*)lb)[3] = b3;
            }
            __syncthreads();
#pragma unroll
            for (int ks = 0; ks < 2; ++ks) {
                bf16x8 af[4], bfr[2];
#pragma unroll
                for (int i = 0; i < 4; ++i)
                    af[i] = *(const bf16x8*)&As[(i * 16 + lr) * 72 + ks * 32 + lq * 8];
#pragma unroll
                for (int j = 0; j < 2; ++j)
                    bfr[j] = *(const bf16x8*)&Bs[(wn + j * 16 + lr) * 72 + ks * 32 + lq * 8];
#pragma unroll
                for (int i = 0; i < 4; ++i)
#pragma unroll
                    for (int j = 0; j < 2; ++j)
                        acc[i][j] = __builtin_amdgcn_mfma_f32_16x16x32_bf16(af[i], bfr[j], acc[i][j], 0, 0, 0);
            }
        }
    }
#pragma unroll
    for (int i = 0; i < 4; ++i)
#pragma unroll
        for (int r = 0; r < 4; ++r) {
            int l = l0 + i * 16 + lq * 4 + r;
            float iv = invU[b * L + l];
#pragma unroll
            for (int j = 0; j < 2; ++j)
                mavb[(size_t)(b * L + l) * D + n0 + wn + j * 16 + lr] = f2b(acc[i][j][r] * iv);
        }
}

// K6: out[row,p] = num / nv1 / nv2.  s1 from s1h+s1l (exact to ~1e-5), mav
// from bf16 mavb.  One wave per row; grid 4096.
__global__ __launch_bounds__(256) void k_out(const unsigned short* __restrict__ s1h,
                                             const unsigned short* __restrict__ s1l,
                                             const unsigned short* __restrict__ mavb,
                                             const float* __restrict__ kern,
                                             float* __restrict__ out) {
    __shared__ float k2s[P * D];
    int tid = threadIdx.x;
#pragma unroll
    for (int p = 0; p < P; ++p) {
        float v = kern[p * D + tid];
        k2s[p * D + tid] = v * v;
    }
    __syncthreads();

    int w = tid >> 6, lane = tid & 63;
    int row = blockIdx.x * 4 + w;
    int dg = lane & 15, ps = lane >> 4;

    float4 sm[4], ss[4], mm[4];
#pragma unroll
    for (int j = 0; j < 4; ++j) {
        ushort4 h4 = *(const ushort4*)(s1h + (size_t)row * D + dg * 4 + j * 64);
        ushort4 l4 = *(const ushort4*)(s1l + (size_t)row * D + dg * 4 + j * 64);
        ushort4 m4 = *(const ushort4*)(mavb + (size_t)row * D + dg * 4 + j * 64);
        float4 sv, mv;
        sv.x = b2f(h4.x) + b2f(l4.x);
        sv.y = b2f(h4.y) + b2f(l4.y);
        sv.z = b2f(h4.z) + b2f(l4.z);
        sv.w = b2f(h4.w) + b2f(l4.w);
        mv.x = b2f(m4.x); mv.y = b2f(m4.y); mv.z = b2f(m4.z); mv.w = b2f(m4.w);
        sm[j].x = sv.x * mv.x; sm[j].y = sv.y * mv.y; sm[j].z = sv.z * mv.z; sm[j].w = sv.w * mv.w;
        ss[j].x = sv.x * sv.x; ss[j].y = sv.y * sv.y; ss[j].z = sv.z * sv.z; ss[j].w = sv.w * sv.w;
        mm[j].x = mv.x * mv.x; mm[j].y = mv.y * mv.y; mm[j].z = mv.z * mv.z; mm[j].w = mv.w * mv.w;
    }
#pragma unroll
    for (int tI = 0; tI < 5; ++tI) {
        int p = ps + tI * 4;
        float na = 0.f, nb = 0.f, nc = 0.f;
#pragma unroll
        for (int j = 0; j < 4; ++j) {
            float4 kv = *(const float4*)&k2s[p * D + j * 64 + dg * 4];
            na += sm[j].x * kv.x + sm[j].y * kv.y + sm[j].z * kv.z + sm[j].w * kv.w;
            nb += ss[j].x * kv.x + ss[j].y * kv.y + ss[j].z * kv.z + ss[j].w * kv.w;
            nc += mm[j].x * kv.x + mm[j].y * kv.y + mm[j].z * kv.z + mm[j].w * kv.w;
        }
#pragma unroll
        for (int o = 8; o; o >>= 1) {
            na += __shfl_down(na, o, 16);
            nb += __shfl_down(nb, o, 16);
            nc += __shfl_down(nc, o, 16);
        }
        if (dg == 0) {
            out[(size_t)row * P + p] = na * rsqrtf(fmaxf(nb, EPS)) *
                                       rsqrtf(fmaxf(nc, EPS));
        }
    }
}

extern "C" void kernel_launch(void* const* d_in, const int* in_sizes, int n_in,
                              void* d_out, int out_size, void* d_ws, size_t ws_size,
                              hipStream_t stream) {
    const float* s1   = (const float*)d_in[0];
    const float* s2   = (const float*)d_in[1];
    const float* kern = (const float*)d_in[2];
    float* out = (float*)d_out;
    float* ws  = (float*)d_ws;

    float* tp   = ws;
    float* invU = ws + 131072;
    unsigned short* s1h  = (unsigned short*)(ws + 147456);
    unsigned short* s1l  = (unsigned short*)(ws + 2244608);
    unsigned short* ChT  = (unsigned short*)(ws + 4341760);
    unsigned short* ClT  = (unsigned short*)(ws + 6438912);
    unsigned short* Gh   = (unsigned short*)(ws + 8536064);
    unsigned short* Gl   = (unsigned short*)(ws + 9060352);
    float* Gp   = ws + 9584640;
    unsigned short* mavb = (unsigned short*)(ws + 13778944);

    k_prep2<<<512, 256, 0, stream>>>(s2, tp, ChT, ClT);
    k_u<<<4096, 256, 0, stream>>>(s1, tp, invU, s1h, s1l);
    k_gram_mfma<<<512, 256, 0, stream>>>(ChT, ClT, Gp);
    k_reduceG<<<1024, 256, 0, stream>>>(Gp, Gh, Gl);
    k_mav_mfma<<<512, 256, 0, stream>>>(s1h, s1l, Gh, Gl, invU, mavb);
    k_out<<<4096, 256, 0, stream>>>(s1h, s1l, mavb, kern, out);
}

// Round 11
// 128.562 us; speedup vs baseline: 1.8598x; 1.1555x over previous
//
#include <hip/hip_runtime.h>
#include <math.h>

#define EPS 1e-7f

constexpr int B = 16, L = 1024, D = 256, P = 20;
constexpr int LD = L * D;     // 262144
constexpr int DD = D * D;     // 65536

typedef __attribute__((ext_vector_type(8))) _Float16 f16x8;
typedef __attribute__((ext_vector_type(4))) float f32x4;

// ---------------------------------------------------------------------------
// ws layout (float slots).  NO atomics, NO memsets.
//   tp    @0         131072    fp32 [32][B][D]  t partials
//   invU  @131072    16384     fp32 [B*L]  1/(s1.t + eps*n1)  (sign used)
//   s1f   @147456    2097152   fp16 [B*L][D]
//   CT    @2244608   2097152   fp16 [B][D][L]  (s2*sqrt(invn2), transposed)
//   Gf    @4341760   524288    fp16 [B][D][D]
//   Gp    @4866048   4194304   fp32 [4][B][D][D]  gram K-split partials
//   mavh  @9060352   2097152   fp16 [B*L][D]  (UNSCALED u — out is
//                                              scale-invariant; sign applied in k_out)
// total 11157504 floats = 44.6 MB
// ---------------------------------------------------------------------------

__device__ inline unsigned short f2h(float x) {
    _Float16 h = (_Float16)x;
    union { _Float16 h; unsigned short u; } c; c.h = h; return c.u;
}
__device__ inline float h2f(unsigned short u) {
    union { unsigned short u; _Float16 h; } c; c.u = u; return (float)c.h;
}

// K1: one pass over s2.  Block = 32 full rows (b, m0..m0+31).  Computes
// invn2 locally, emits tp partials and transposed fp16 CT.  Grid 512.
__global__ __launch_bounds__(256) void k_prep2(const float* __restrict__ s2,
                                               float* __restrict__ tp,
                                               unsigned short* __restrict__ CT) {
    __shared__ float tile[32][257];
    __shared__ float wiv[32];   // invn2 = 1/norm
    __shared__ float wsq[32];   // sqrt(invn2)
    int tid = threadIdx.x;
    int b   = blockIdx.x >> 5, mt = blockIdx.x & 31;
    int m0  = mt * 32;
    {
        int r = tid >> 3, c0 = (tid & 7) * 32;
        const float* gp = s2 + (size_t)b * LD + (size_t)(m0 + r) * D + c0;
        float4 v[8];
#pragma unroll
        for (int q = 0; q < 8; ++q) v[q] = ((const float4*)gp)[q];
#pragma unroll
        for (int q = 0; q < 8; ++q) *(float4*)&tile[r][c0 + q * 4] = v[q];
    }
    __syncthreads();
    {
        int r = tid >> 3, seg = tid & 7;
        float s = 0.f;
#pragma unroll
        for (int k = 0; k < 32; ++k) { float v = tile[r][seg * 32 + k]; s += v * v; }
#pragma unroll
        for (int o = 4; o; o >>= 1) s += __shfl_down(s, o, 8);
        if (seg == 0) {
            float iv = 1.0f / sqrtf(fmaxf(s, EPS));
            wiv[r] = iv;
            wsq[r] = sqrtf(iv);
        }
    }
    __syncthreads();
    {
        int dc = tid;                          // d-column 0..255
        float tpart = 0.f;
        union { unsigned short us[32]; uint4 q[4]; } ph;
#pragma unroll
        for (int m = 0; m < 32; ++m) {
            float v = tile[m][dc];
            tpart += v * wiv[m];
            ph.us[m] = f2h(v * wsq[m]);
        }
        tp[(size_t)(mt * B + b) * D + dc] = tpart;
        size_t o = (size_t)b * LD + (size_t)dc * L + m0;
        *(uint4*)(CT + o)      = ph.q[0]; *(uint4*)(CT + o + 8)  = ph.q[1];
        *(uint4*)(CT + o + 16) = ph.q[2]; *(uint4*)(CT + o + 24) = ph.q[3];
    }
}

// K2: one pass over s1.  Reduces t-partials, computes invU (fp32, exact sign
// path), writes fp16 s1f.  One wave per row; grid 4096.
__global__ __launch_bounds__(256) void k_u(const float* __restrict__ s1,
                                           const float* __restrict__ tp,
                                           float* __restrict__ invU,
                                           unsigned short* __restrict__ s1f) {
    __shared__ float ts[D];
    int tid = threadIdx.x;
    {
        int b0 = (blockIdx.x * 4) >> 10;      // all 4 rows share b
        float acc = 0.f;
#pragma unroll
        for (int mc = 0; mc < 32; ++mc)
            acc += tp[(size_t)(mc * B + b0) * D + tid];
        ts[tid] = acc;
    }
    __syncthreads();

    int w = tid >> 6, lane = tid & 63;
    int row = blockIdx.x * 4 + w;             // 0..16383
    int dg = lane & 15;

    float4 sv[4];
    float up = 0.f, sq = 0.f;
#pragma unroll
    for (int j = 0; j < 4; ++j) {
        sv[j] = *(const float4*)(s1 + (size_t)row * D + dg * 4 + j * 64);
        float4 tv = *(const float4*)(ts + dg * 4 + j * 64);
        up += sv[j].x * tv.x + sv[j].y * tv.y + sv[j].z * tv.z + sv[j].w * tv.w;
        sq += sv[j].x * sv[j].x + sv[j].y * sv[j].y + sv[j].z * sv[j].z + sv[j].w * sv[j].w;
    }
#pragma unroll
    for (int o = 8; o; o >>= 1) {
        up += __shfl_down(up, o, 16);
        sq += __shfl_down(sq, o, 16);
    }
    if (lane == 0) {
        float n1v = sqrtf(fmaxf(sq, EPS));
        invU[row] = 1.0f / (up + EPS * n1v);
    }
#pragma unroll
    for (int j = 0; j < 4; ++j) {
        ushort4 h4;
        h4.x = f2h(sv[j].x); h4.y = f2h(sv[j].y);
        h4.z = f2h(sv[j].z); h4.w = f2h(sv[j].w);
        *(ushort4*)(s1f + (size_t)row * D + dg * 4 + j * 64) = h4;
    }
}

// K3: Gram via fp16 MFMA, single pass.  G = C'C, K-split x4 (256 m each).
// Block: 128(i) x 64(j) tile, 4 waves 2x2 (64x32 each, 4x2 MFMA 16x16x32).
// Grid: 16 b x (2 ti x 4 tj x 4 kc) = 512 -> 2 blocks/CU.
__global__ __launch_bounds__(256) void k_gram_mfma(const unsigned short* __restrict__ CT,
                                                   float* __restrict__ Gp) {
    __shared__ short As[128 * 72];
    __shared__ short Bs[64 * 72];
    int tid  = threadIdx.x;
    int b    = blockIdx.x >> 5;
    int rem  = blockIdx.x & 31;
    int ti   = rem >> 4;               // 0..1
    int tj   = (rem >> 2) & 3;         // 0..3
    int kc   = rem & 3;                // 0..3
    int wave = tid >> 6, lane = tid & 63;
    int wr   = (wave >> 1) * 64, wcc = (wave & 1) * 32;
    int lr   = lane & 15, lq = lane >> 4;
    int arow = tid >> 1, ahalf = (tid & 1) * 32;   // A: 128 rows, 2 thr/row
    int brow = tid >> 2, bq = (tid & 3) * 16;      // B: 64 rows, 4 thr/row

    f32x4 acc[4][2];
#pragma unroll
    for (int i = 0; i < 4; ++i)
#pragma unroll
        for (int j = 0; j < 2; ++j) acc[i][j] = (f32x4){0.f, 0.f, 0.f, 0.f};

#pragma unroll 1
    for (int kb = 0; kb < 4; ++kb) {
        int koff = kc * 256 + kb * 64;
        __syncthreads();
        {
            const unsigned short* ga = CT + (size_t)b * LD + (size_t)(ti * 128 + arow) * L + koff + ahalf;
            uint4 a0 = ((const uint4*)ga)[0], a1 = ((const uint4*)ga)[1];
            uint4 a2 = ((const uint4*)ga)[2], a3 = ((const uint4*)ga)[3];
            const unsigned short* gb = CT + (size_t)b * LD + (size_t)(tj * 64 + brow) * L + koff + bq;
            uint4 b0 = ((const uint4*)gb)[0], b1 = ((const uint4*)gb)[1];
            short* la = &As[arow * 72 + ahalf];
            ((uint4*)la)[0] = a0; ((uint4*)la)[1] = a1;
            ((uint4*)la)[2] = a2; ((uint4*)la)[3] = a3;
            short* lb = &Bs[brow * 72 + bq];
            ((uint4*)lb)[0] = b0; ((uint4*)lb)[1] = b1;
        }
        __syncthreads();
#pragma unroll
        for (int ks = 0; ks < 2; ++ks) {
            f16x8 af[4], bfr[2];
#pragma unroll
            for (int i = 0; i < 4; ++i)
                af[i] = *(const f16x8*)&As[(wr + i * 16 + lr) * 72 + ks * 32 + lq * 8];
#pragma unroll
            for (int j = 0; j < 2; ++j)
                bfr[j] = *(const f16x8*)&Bs[(wcc + j * 16 + lr) * 72 + ks * 32 + lq * 8];
#pragma unroll
            for (int i = 0; i < 4; ++i)
#pragma unroll
                for (int j = 0; j < 2; ++j)
                    acc[i][j] = __builtin_amdgcn_mfma_f32_16x16x32_f16(af[i], bfr[j], acc[i][j], 0, 0, 0);
        }
    }
    float* gout = Gp + ((size_t)(kc * B + b)) * DD;
#pragma unroll
    for (int i = 0; i < 4; ++i)
#pragma unroll
        for (int r = 0; r < 4; ++r) {
            int row = ti * 128 + wr + i * 16 + lq * 4 + r;
#pragma unroll
            for (int j = 0; j < 2; ++j)
                gout[(size_t)row * D + tj * 64 + wcc + j * 16 + lr] = acc[i][j][r];
        }
}

// K4: reduce 4 gram partials; emit fp16 Gf.
__global__ __launch_bounds__(256) void k_reduceG(const float* __restrict__ Gp,
                                                 unsigned short* __restrict__ Gf) {
    size_t i = ((size_t)blockIdx.x * 256 + threadIdx.x) * 4;
    float4 s = *(const float4*)(Gp + i);
#pragma unroll
    for (int kc = 1; kc < 4; ++kc) {
        float4 a = *(const float4*)(Gp + (size_t)kc * B * DD + i);
        s.x += a.x; s.y += a.y; s.z += a.z; s.w += a.w;
    }
    ushort4 h4;
    h4.x = f2h(s.x); h4.y = f2h(s.y); h4.z = f2h(s.z); h4.w = f2h(s.w);
    *(ushort4*)(Gf + i) = h4;
}

// K5: mavh = fp16(s1 @ G)  (UNSCALED — invU sign applied in k_out; out is
// scale-invariant in mav so the magnitude of invU never matters).
// Block = 64 l x 128 n, 4 waves each 64l x 32n (4x2 MFMA).  Grid 512.
__global__ __launch_bounds__(256) void k_mav_mfma(const unsigned short* __restrict__ s1f,
                                                  const unsigned short* __restrict__ Gf,
                                                  unsigned short* __restrict__ mavh) {
    __shared__ short As[64 * 72];
    __shared__ short Bs[128 * 72];
    int tid  = threadIdx.x;
    int b    = blockIdx.x >> 5;
    int rem  = blockIdx.x & 31;
    int lt   = rem >> 1, nt = rem & 1;
    int l0   = lt * 64, n0 = nt * 128;
    int wave = tid >> 6, lane = tid & 63;
    int wn   = wave * 32;
    int lr   = lane & 15, lq = lane >> 4;
    int arow = tid >> 2, aq = (tid & 3) * 16;      // A: 64 rows x 64 shorts
    int brow = tid >> 1, bhalf = (tid & 1) * 32;   // B: 128 rows x 64 shorts

    f32x4 acc[4][2];
#pragma unroll
    for (int i = 0; i < 4; ++i)
#pragma unroll
        for (int j = 0; j < 2; ++j) acc[i][j] = (f32x4){0.f, 0.f, 0.f, 0.f};

#pragma unroll 1
    for (int kb = 0; kb < 4; ++kb) {
        int koff = kb * 64;
        __syncthreads();
        {
            const unsigned short* ga = s1f + (size_t)(b * L + l0 + arow) * D + koff + aq;
            uint4 a0 = ((const uint4*)ga)[0], a1 = ((const uint4*)ga)[1];
            const unsigned short* gb = Gf + (size_t)b * DD + (size_t)(n0 + brow) * D + koff + bhalf;
            uint4 b0 = ((const uint4*)gb)[0], b1 = ((const uint4*)gb)[1];
            uint4 b2 = ((const uint4*)gb)[2], b3 = ((const uint4*)gb)[3];
            short* la = &As[arow * 72 + aq];
            ((uint4*)la)[0] = a0; ((uint4*)la)[1] = a1;
            short* lb = &Bs[brow * 72 + bhalf];
            ((uint4*)lb)[0] = b0; ((uint4*)lb)[1] = b1;
            ((uint4*)lb)[2] = b2; ((uint4*)lb)[3] = b3;
        }
        __syncthreads();
#pragma unroll
        for (int ks = 0; ks < 2; ++ks) {
            f16x8 af[4], bfr[2];
#pragma unroll
            for (int i = 0; i < 4; ++i)
                af[i] = *(const f16x8*)&As[(i * 16 + lr) * 72 + ks * 32 + lq * 8];
#pragma unroll
            for (int j = 0; j < 2; ++j)
                bfr[j] = *(const f16x8*)&Bs[(wn + j * 16 + lr) * 72 + ks * 32 + lq * 8];
#pragma unroll
            for (int i = 0; i < 4; ++i)
#pragma unroll
                for (int j = 0; j < 2; ++j)
                    acc[i][j] = __builtin_amdgcn_mfma_f32_16x16x32_f16(af[i], bfr[j], acc[i][j], 0, 0, 0);
        }
    }
#pragma unroll
    for (int i = 0; i < 4; ++i)
#pragma unroll
        for (int r = 0; r < 4; ++r) {
            int l = l0 + i * 16 + lq * 4 + r;
#pragma unroll
            for (int j = 0; j < 2; ++j)
                mavh[(size_t)(b * L + l) * D + n0 + wn + j * 16 + lr] = f2h(acc[i][j][r]);
        }
}

// K6: out[row,p] = sign(invU) * na * rsqrt(nb) * rsqrt(nc) over fp16 s1f/mavh.
__global__ __launch_bounds__(256) void k_out(const unsigned short* __restrict__ s1f,
                                             const unsigned short* __restrict__ mavh,
                                             const float* __restrict__ invU,
                                             const float* __restrict__ kern,
                                             float* __restrict__ out) {
    __shared__ float k2s[P * D];
    int tid = threadIdx.x;
#pragma unroll
    for (int p = 0; p < P; ++p) {
        float v = kern[p * D + tid];
        k2s[p * D + tid] = v * v;
    }
    __syncthreads();

    int w = tid >> 6, lane = tid & 63;
    int row = blockIdx.x * 4 + w;
    int dg = lane & 15, ps = lane >> 4;

    float4 sm[4], ss[4], mm[4];
#pragma unroll
    for (int j = 0; j < 4; ++j) {
        ushort4 h4 = *(const ushort4*)(s1f + (size_t)row * D + dg * 4 + j * 64);
        ushort4 m4 = *(const ushort4*)(mavh + (size_t)row * D + dg * 4 + j * 64);
        float4 sv, mv;
        sv.x = h2f(h4.x); sv.y = h2f(h4.y); sv.z = h2f(h4.z); sv.w = h2f(h4.w);
        mv.x = h2f(m4.x); mv.y = h2f(m4.y); mv.z = h2f(m4.z); mv.w = h2f(m4.w);
        sm[j].x = sv.x * mv.x; sm[j].y = sv.y * mv.y; sm[j].z = sv.z * mv.z; sm[j].w = sv.w * mv.w;
        ss[j].x = sv.x * sv.x; ss[j].y = sv.y * sv.y; ss[j].z = sv.z * sv.z; ss[j].w = sv.w * sv.w;
        mm[j].x = mv.x * mv.x; mm[j].y = mv.y * mv.y; mm[j].z = mv.z * mv.z; mm[j].w = mv.w * mv.w;
    }
    float sgn = (invU[row] < 0.f) ? -1.f : 1.f;
#pragma unroll
    for (int tI = 0; tI < 5; ++tI) {
        int p = ps + tI * 4;
        float na = 0.f, nb = 0.f, nc = 0.f;
#pragma unroll
        for (int j = 0; j < 4; ++j) {
            float4 kv = *(const float4*)&k2s[p * D + j * 64 + dg * 4];
            na += sm[j].x * kv.x + sm[j].y * kv.y + sm[j].z * kv.z + sm[j].w * kv.w;
            nb += ss[j].x * kv.x + ss[j].y * kv.y + ss[j].z * kv.z + ss[j].w * kv.w;
            nc += mm[j].x * kv.x + mm[j].y * kv.y + mm[j].z * kv.z + mm[j].w * kv.w;
        }
#pragma unroll
        for (int o = 8; o; o >>= 1) {
            na += __shfl_down(na, o, 16);
            nb += __shfl_down(nb, o, 16);
            nc += __shfl_down(nc, o, 16);
        }
        if (dg == 0) {
            out[(size_t)row * P + p] = sgn * na * rsqrtf(fmaxf(nb, EPS)) *
                                       rsqrtf(fmaxf(nc, EPS));
        }
    }
}

extern "C" void kernel_launch(void* const* d_in, const int* in_sizes, int n_in,
                              void* d_out, int out_size, void* d_ws, size_t ws_size,
                              hipStream_t stream) {
    const float* s1   = (const float*)d_in[0];
    const float* s2   = (const float*)d_in[1];
    const float* kern = (const float*)d_in[2];
    float* out = (float*)d_out;
    float* ws  = (float*)d_ws;

    float* tp   = ws;
    float* invU = ws + 131072;
    unsigned short* s1f  = (unsigned short*)(ws + 147456);
    unsigned short* CT   = (unsigned short*)(ws + 2244608);
    unsigned short* Gf   = (unsigned short*)(ws + 4341760);
    float* Gp   = ws + 4866048;
    unsigned short* mavh = (unsigned short*)(ws + 9060352);

    k_prep2<<<512, 256, 0, stream>>>(s2, tp, CT);
    k_u<<<4096, 256, 0, stream>>>(s1, tp, invU, s1f);
    k_gram_mfma<<<512, 256, 0, stream>>>(CT, Gp);
    k_reduceG<<<1024, 256, 0, stream>>>(Gp, Gf);
    k_mav_mfma<<<512, 256, 0, stream>>>(s1f, Gf, mavh);
    k_out<<<4096, 256, 0, stream>>>(s1f, mavh, invU, kern, out);
}